// Round 1
// baseline (2762.349 us; speedup 1.0000x reference)
//
#include <hip/hip_runtime.h>

#define GAMMA 0.25f

// ---------------------------------------------------------------------------
// Shapes: B=1024, C=3, H=64, D=256, NP=64 (8x8 grid of 8x8 patches),
//         M=1024, NH=8, R=32, P=8.  All fp32.  out[b] = quad - coupling.
// ---------------------------------------------------------------------------

__device__ __forceinline__ float dot4(float4 a, float4 b) {
  return fmaf(a.x, b.x, fmaf(a.y, b.y, fmaf(a.z, b.z, a.w * b.w)));
}

// 256-thread block sum. Valid on all threads after return (used on t==0).
__device__ __forceinline__ float block_sum_256(float v, float* tmp) {
#pragma unroll
  for (int off = 32; off; off >>= 1) v += __shfl_down(v, off, 64);
  int w = threadIdx.x >> 6;
  if ((threadIdx.x & 63) == 0) tmp[w] = v;
  __syncthreads();
  return tmp[0] + tmp[1] + tmp[2] + tmp[3];
}

// ---------------------------------------------------------------------------
// Kernel 1: quad_x + quad_z - phi_vis - phi_bias - phi_pos.
// One block per batch. Sole non-atomic writer -> initializes out[b].
// ---------------------------------------------------------------------------
__global__ __launch_bounds__(256) void k_xz(const float* __restrict__ x,
                                            const float* __restrict__ z,
                                            const float* __restrict__ vb,
                                            const float* __restrict__ eb,
                                            const float* __restrict__ pb,
                                            float* __restrict__ out) {
  __shared__ float tmp[4];
  int b = blockIdx.x, t = threadIdx.x;
  const float4* xb = (const float4*)(x + (size_t)b * 12288);
  const float4* vb4 = (const float4*)vb;
  float s = 0.f;
  for (int i = t; i < 3072; i += 256) {
    float4 xv = xb[i];
    float4 bv = vb4[i];
    s += 0.5f * dot4(xv, xv) - dot4(bv, xv);
  }
  const float4* zb = (const float4*)(z + (size_t)b * 16384);
  const float4* pb4 = (const float4*)pb;
  const float4* eb4 = (const float4*)eb;
  for (int i = t; i < 4096; i += 256) {
    float4 zv = zb[i];
    float4 pv = pb4[i];
    float4 ev = eb4[i & 63];  // d-part broadcast of encoder_bias
    float4 c;
    c.x = pv.x + ev.x; c.y = pv.y + ev.y; c.z = pv.z + ev.z; c.w = pv.w + ev.w;
    s += 0.5f * dot4(zv, zv) - dot4(zv, c);
  }
  float r = block_sum_256(s, tmp);
  if (t == 0) out[b] = r;
}

// ---------------------------------------------------------------------------
// Kernel 2: phi_enc = sum_{p,d} (conv patch-GEMM)[p,d] * z[b,p,d].
// One block per batch; thread t owns output channel d=t.
// Patch values are wave-uniform -> scalar loads; weight reads coalesced-ish
// float4 (L2-hot 196 KB), 64 fp32 accumulators over the 64 patches.
// ---------------------------------------------------------------------------
__global__ __launch_bounds__(256) void k_enc(const float* __restrict__ x,
                                             const float* __restrict__ z,
                                             const float* __restrict__ ew,
                                             float* __restrict__ out) {
  __shared__ float tmp[4];
  int b = blockIdx.x, t = threadIdx.x;
  const float* xb = x + (size_t)b * 12288;
  float acc[64];
#pragma unroll
  for (int p = 0; p < 64; ++p) acc[p] = 0.f;

  // k = c*64 + i*8 + j ranges over the 192 patch elements; k4 = k/4.
  for (int k4 = 0; k4 < 48; ++k4) {
    float4 wv = *(const float4*)(ew + (size_t)t * 192 + k4 * 4);  // w[d=t, 4k4..+3]
    int c = k4 >> 4;
    int ii = (k4 >> 1) & 7;
    int jh = (k4 & 1) * 4;
    const float* base = xb + c * 4096 + ii * 64 + jh;
#pragma unroll
    for (int p = 0; p < 64; ++p) {  // p = gi*8+gj
      float4 pv = *(const float4*)(base + (p >> 3) * 512 + (p & 7) * 8);
      acc[p] = fmaf(wv.x, pv.x,
               fmaf(wv.y, pv.y, fmaf(wv.z, pv.z, fmaf(wv.w, pv.w, acc[p]))));
    }
  }
  const float* zb = z + (size_t)b * 16384;
  float s = 0.f;
#pragma unroll
  for (int p = 0; p < 64; ++p) s += acc[p] * zb[p * 256 + t];
  float r = block_sum_256(s, tmp);
  if (t == 0) atomicAdd(out + b, -r);
}

// ---------------------------------------------------------------------------
// Kernel 3: phi_mem = sum relu(z @ memory_weight)^2, fused (no (B,NP,M) tensor).
// One block per batch; thread t owns m = 4t..4t+3 (memory_weight is already
// k-major: coalesced float4). z values wave-uniform -> scalar loads.
// 4 p-tiles of 16 -> 64 accumulators.
// ---------------------------------------------------------------------------
__global__ __launch_bounds__(256) void k_mem(const float* __restrict__ z,
                                             const float* __restrict__ mw,
                                             float* __restrict__ out) {
  __shared__ float tmp[4];
  int b = blockIdx.x, t = threadIdx.x;
  const float4* m4 = (const float4*)mw;  // [k*256 + t] -> mw[k*1024 + 4t..]
  const float* zb = z + (size_t)b * 16384;
  float total = 0.f;
  for (int pt = 0; pt < 4; ++pt) {
    float4 acc[16];
#pragma unroll
    for (int pp = 0; pp < 16; ++pp) acc[pp] = make_float4(0.f, 0.f, 0.f, 0.f);
    const float* zp0 = zb + pt * 4096;
    for (int k = 0; k < 256; ++k) {
      float4 w = m4[k * 256 + t];
#pragma unroll
      for (int pp = 0; pp < 16; ++pp) {
        float zv = zp0[pp * 256 + k];
        acc[pp].x = fmaf(zv, w.x, acc[pp].x);
        acc[pp].y = fmaf(zv, w.y, acc[pp].y);
        acc[pp].z = fmaf(zv, w.z, acc[pp].z);
        acc[pp].w = fmaf(zv, w.w, acc[pp].w);
      }
    }
#pragma unroll
    for (int pp = 0; pp < 16; ++pp) {
      float r;
      r = fmaxf(acc[pp].x, 0.f); total = fmaf(r, r, total);
      r = fmaxf(acc[pp].y, 0.f); total = fmaf(r, r, total);
      r = fmaxf(acc[pp].z, 0.f); total = fmaf(r, r, total);
      r = fmaxf(acc[pp].w, 0.f); total = fmaf(r, r, total);
    }
  }
  float r = block_sum_256(total, tmp);
  if (t == 0) atomicAdd(out + b, -r);
}

// ---------------------------------------------------------------------------
// Kernel 4: phi_att. One block per (b,h).
// Phase 1 (x2, Q then K): stage W[h] (32x256) in LDS w/ stride-260 padding
// (conflict-free ds_read_b128), compute 32x64 fragments into Qs/Ks (pad 65).
// Phase 2: A[m,n] over r=32 from LDS; logsumexp over n via wave shuffles.
// ---------------------------------------------------------------------------
__global__ __launch_bounds__(256) void k_attn(const float* __restrict__ z,
                                              const float* __restrict__ wq,
                                              const float* __restrict__ wk,
                                              float* __restrict__ out) {
  __shared__ float Wl[32 * 260];
  __shared__ float Qs[32 * 65];
  __shared__ float Ks[32 * 65];
  __shared__ float red[4];
  int b = blockIdx.x >> 3, h = blockIdx.x & 7;
  int t = threadIdx.x;
  const float4* zb4 = (const float4*)(z + (size_t)b * 16384);
  int r = t & 31, pg = t >> 5;  // 32 rows x 8 patch-groups of 8

  for (int mat = 0; mat < 2; ++mat) {
    const float4* W4 = (const float4*)((mat ? wk : wq) + (size_t)h * 8192);
    __syncthreads();  // protect Wl from previous iteration's readers
    for (int idx = t; idx < 2048; idx += 256) {
      int rr = idx >> 6, dd = idx & 63;
      *(float4*)&Wl[rr * 260 + dd * 4] = W4[idx];
    }
    __syncthreads();
    float acc[8];
#pragma unroll
    for (int pp = 0; pp < 8; ++pp) acc[pp] = 0.f;
    for (int d4 = 0; d4 < 64; ++d4) {
      float4 wv = *(const float4*)&Wl[r * 260 + d4 * 4];
#pragma unroll
      for (int pp = 0; pp < 8; ++pp) {
        float4 zv = zb4[(pg * 8 + pp) * 64 + d4];
        acc[pp] = fmaf(wv.x, zv.x,
                  fmaf(wv.y, zv.y, fmaf(wv.z, zv.z, fmaf(wv.w, zv.w, acc[pp]))));
      }
    }
    float* Dst = mat ? Ks : Qs;
#pragma unroll
    for (int pp = 0; pp < 8; ++pp) Dst[r * 65 + pg * 8 + pp] = acc[pp];
  }
  __syncthreads();

  // Phase 2: lane = n, wave wg owns rows m = wg*16..+15.
  int n = t & 63, wg = t >> 6;
  float a[16];
#pragma unroll
  for (int mm = 0; mm < 16; ++mm) a[mm] = 0.f;
  for (int rr = 0; rr < 32; ++rr) {
    float kv = Ks[rr * 65 + n];
#pragma unroll
    for (int mm = 0; mm < 16; ++mm)
      a[mm] = fmaf(Qs[rr * 65 + wg * 16 + mm], kv, a[mm]);
  }
  float lse_acc = 0.f;
#pragma unroll
  for (int mm = 0; mm < 16; ++mm) {
    float v = GAMMA * a[mm];
    float mx = v;
#pragma unroll
    for (int off = 32; off; off >>= 1) mx = fmaxf(mx, __shfl_xor(mx, off, 64));
    float e = __expf(v - mx);
#pragma unroll
    for (int off = 32; off; off >>= 1) e += __shfl_xor(e, off, 64);
    lse_acc += mx + __logf(e);
  }
  if ((t & 63) == 0) red[wg] = lse_acc;
  __syncthreads();
  if (t == 0) {
    float tot = (red[0] + red[1] + red[2] + red[3]) * (1.0f / GAMMA);
    atomicAdd(out + b, -tot);
  }
}

// ---------------------------------------------------------------------------
extern "C" void kernel_launch(void* const* d_in, const int* in_sizes, int n_in,
                              void* d_out, int out_size, void* d_ws,
                              size_t ws_size, hipStream_t stream) {
  (void)in_sizes; (void)n_in; (void)out_size; (void)d_ws; (void)ws_size;
  const float* x  = (const float*)d_in[0];
  const float* z  = (const float*)d_in[1];
  const float* ew = (const float*)d_in[2];
  const float* eb = (const float*)d_in[3];
  const float* vb = (const float*)d_in[4];
  const float* pb = (const float*)d_in[5];
  const float* mw = (const float*)d_in[6];
  const float* wq = (const float*)d_in[7];
  const float* wk = (const float*)d_in[8];
  float* out = (float*)d_out;

  k_xz  <<<1024, 256, 0, stream>>>(x, z, vb, eb, pb, out);   // writes out[b]
  k_enc <<<1024, 256, 0, stream>>>(x, z, ew, out);           // atomic -=
  k_mem <<<1024, 256, 0, stream>>>(z, mw, out);              // atomic -=
  k_attn<<<8192, 256, 0, stream>>>(z, wq, wk, out);          // atomic -=
}

// Round 3
// 1898.658 us; speedup vs baseline: 1.4549x; 1.4549x over previous
//
#include <hip/hip_runtime.h>

#define GAMMA 0.25f

// Shapes: B=1024, C=3, H=64, D=256, NP=64 (8x8 grid of 8x8 patches),
//         M=1024, NH=8, R=32, P=8.  All fp32.  out[b] = quad - coupling.

__device__ __forceinline__ float dot4(float4 a, float4 b) {
  return fmaf(a.x, b.x, fmaf(a.y, b.y, fmaf(a.z, b.z, a.w * b.w)));
}

__device__ __forceinline__ void fma4(float4& a, float s, float4 w) {
  a.x = fmaf(s, w.x, a.x); a.y = fmaf(s, w.y, a.y);
  a.z = fmaf(s, w.z, a.z); a.w = fmaf(s, w.w, a.w);
}

// 256-thread block sum; result valid on all threads.
__device__ __forceinline__ float block_sum_256(float v, float* tmp) {
#pragma unroll
  for (int off = 32; off; off >>= 1) v += __shfl_down(v, off, 64);
  int w = threadIdx.x >> 6;
  if ((threadIdx.x & 63) == 0) tmp[w] = v;
  __syncthreads();
  return tmp[0] + tmp[1] + tmp[2] + tmp[3];
}

// ---------------------------------------------------------------------------
// Kernel 1: quad_x + quad_z - phi_vis - phi_bias - phi_pos. Memory-bound.
// Sole non-atomic writer -> initializes out[b].
// ---------------------------------------------------------------------------
__global__ __launch_bounds__(256) void k_xz(const float* __restrict__ x,
                                            const float* __restrict__ z,
                                            const float* __restrict__ vb,
                                            const float* __restrict__ eb,
                                            const float* __restrict__ pb,
                                            float* __restrict__ out) {
  __shared__ float tmp[4];
  int b = blockIdx.x, t = threadIdx.x;
  const float4* xb = (const float4*)(x + (size_t)b * 12288);
  const float4* vb4 = (const float4*)vb;
  float s = 0.f;
  for (int i = t; i < 3072; i += 256) {
    float4 xv = xb[i];
    float4 bv = vb4[i];
    s += 0.5f * dot4(xv, xv) - dot4(bv, xv);
  }
  const float4* zb = (const float4*)(z + (size_t)b * 16384);
  const float4* pb4 = (const float4*)pb;
  const float4* eb4 = (const float4*)eb;
  for (int i = t; i < 4096; i += 256) {
    float4 zv = zb[i];
    float4 pv = pb4[i];
    float4 ev = eb4[i & 63];
    float4 c;
    c.x = pv.x + ev.x; c.y = pv.y + ev.y; c.z = pv.z + ev.z; c.w = pv.w + ev.w;
    s += 0.5f * dot4(zv, zv) - dot4(zv, c);
  }
  float r = block_sum_256(s, tmp);
  if (t == 0) out[b] = r;
}

// ---------------------------------------------------------------------------
// Kernel 2: phi_enc. One block per batch; x[b] staged in LDS (48 KB) so the
// inner loop is 1 global dwordx4 (w) + 64 LDS b128 broadcasts + 256 FMA.
// Thread t owns output channel d=t, acc over the 64 patches.
// ---------------------------------------------------------------------------
__global__ __launch_bounds__(256) void k_enc(const float* __restrict__ x,
                                             const float* __restrict__ z,
                                             const float* __restrict__ ew,
                                             float* __restrict__ out) {
  __shared__ float xs[12288];  // 48 KB: raw x[b] copy [c][64][64]
  __shared__ float tmp[4];
  int b = blockIdx.x, t = threadIdx.x;
  const float4* xb4 = (const float4*)(x + (size_t)b * 12288);
  for (int i = t; i < 3072; i += 256) ((float4*)xs)[i] = xb4[i];
  __syncthreads();

  float acc[64];
#pragma unroll
  for (int p = 0; p < 64; ++p) acc[p] = 0.f;

  // k = c*64 + i*8 + j over the 192 patch elements; k4 = k/4.
  for (int k4 = 0; k4 < 48; ++k4) {
    float4 wv = *(const float4*)(ew + (size_t)t * 192 + k4 * 4);
    int c = k4 >> 4;
    int ii = (k4 >> 1) & 7;
    int jh = (k4 & 1) * 4;
    const float* base = xs + c * 4096 + ii * 64 + jh;
#pragma unroll
    for (int p = 0; p < 64; ++p) {  // p = gi*8+gj
      float4 pv = *(const float4*)(base + (p >> 3) * 512 + (p & 7) * 8);
      acc[p] = fmaf(wv.x, pv.x,
               fmaf(wv.y, pv.y, fmaf(wv.z, pv.z, fmaf(wv.w, pv.w, acc[p]))));
    }
  }
  const float* zb = z + (size_t)b * 16384;
  float s = 0.f;
#pragma unroll
  for (int p = 0; p < 64; ++p) s += acc[p] * zb[p * 256 + t];
  float r = block_sum_256(s, tmp);
  if (t == 0) atomicAdd(out + b, -r);
}

// ---------------------------------------------------------------------------
// Kernel 3: phi_mem = sum relu(z @ mw)^2, fused. Block = (b, p-tile of 16).
// z-tile staged in LDS (16 KB); inner k4-loop: 4 coalesced w float4 loads +
// 16 LDS b128 broadcasts + 256 FMA. Thread t owns m = 4t..4t+3.
// ---------------------------------------------------------------------------
__global__ __launch_bounds__(256) void k_mem(const float* __restrict__ z,
                                             const float* __restrict__ mw,
                                             float* __restrict__ out) {
  __shared__ float zs[16 * 256];  // [p][k], 16 KB
  __shared__ float tmp[4];
  int b = blockIdx.x >> 2, pt = blockIdx.x & 3, t = threadIdx.x;
  const float4* zb4 = (const float4*)(z + (size_t)b * 16384 + pt * 4096);
  for (int i = t; i < 1024; i += 256) ((float4*)zs)[i] = zb4[i];
  __syncthreads();

  const float4* m4 = (const float4*)mw;  // [k*256 + t] -> mw[k*1024 + 4t..]
  float4 acc[16];
#pragma unroll
  for (int pp = 0; pp < 16; ++pp) acc[pp] = make_float4(0.f, 0.f, 0.f, 0.f);

#pragma unroll 2
  for (int k4 = 0; k4 < 64; ++k4) {
    float4 w0 = m4[(4 * k4 + 0) * 256 + t];
    float4 w1 = m4[(4 * k4 + 1) * 256 + t];
    float4 w2 = m4[(4 * k4 + 2) * 256 + t];
    float4 w3 = m4[(4 * k4 + 3) * 256 + t];
#pragma unroll
    for (int pp = 0; pp < 16; ++pp) {
      float4 zv = *(const float4*)&zs[pp * 256 + k4 * 4];
      fma4(acc[pp], zv.x, w0);
      fma4(acc[pp], zv.y, w1);
      fma4(acc[pp], zv.z, w2);
      fma4(acc[pp], zv.w, w3);
    }
  }
  float total = 0.f;
#pragma unroll
  for (int pp = 0; pp < 16; ++pp) {
    float r;
    r = fmaxf(acc[pp].x, 0.f); total = fmaf(r, r, total);
    r = fmaxf(acc[pp].y, 0.f); total = fmaf(r, r, total);
    r = fmaxf(acc[pp].z, 0.f); total = fmaf(r, r, total);
    r = fmaxf(acc[pp].w, 0.f); total = fmaf(r, r, total);
  }
  float r = block_sum_256(total, tmp);
  if (t == 0) atomicAdd(out + b, -r);
}

// ---------------------------------------------------------------------------
// Kernel 4: phi_att. Block = (b, half): handles 4 heads. Phase 1: z[b] staged
// in LDS d-major (two 32 KB chunks, XOR-swizzled: conflict-free hot reads,
// 4-way staging writes), Q/K for all 4 heads accumulated in registers
// (wave w owns rows w*8..w*8+7, lane = patch). W read as 16-B wave-uniform
// broadcasts (L2-hot). Phase 2 per head: Qs/Ks reuse the same LDS,
// A = Q^T K, logsumexp over n via full-wave shuffles.
// ---------------------------------------------------------------------------
__global__ __launch_bounds__(256) void k_attn(const float* __restrict__ z,
                                              const float* __restrict__ wq,
                                              const float* __restrict__ wk,
                                              float* __restrict__ out) {
  __shared__ float lds[8192];  // 32 KB
  __shared__ float red[4];
  const int b = blockIdx.x >> 1, half = blockIdx.x & 1;
  const int t = threadIdx.x;
  const int lane = t & 63;  // p (phase 1) / n (phase 2)
  const int w = t >> 6;
  const float4* zb4 = (const float4*)(z + (size_t)b * 16384);

  float qa[4][8], ka[4][8];
#pragma unroll
  for (int hh = 0; hh < 4; ++hh)
#pragma unroll
    for (int j = 0; j < 8; ++j) { qa[hh][j] = 0.f; ka[hh][j] = 0.f; }

  float4* lds4 = (float4*)lds;
  for (int dc = 0; dc < 2; ++dc) {
    __syncthreads();
    for (int i = t; i < 2048; i += 256) {
      int p = i >> 5, ld4 = i & 31;
      lds4[ld4 * 64 + (p ^ (ld4 & 7))] = zb4[p * 64 + dc * 32 + ld4];
    }
    __syncthreads();
#pragma unroll
    for (int hh = 0; hh < 4; ++hh) {
      int h = half * 4 + hh;
      const float4* Wq4 = (const float4*)(wq + (size_t)h * 8192);  // [r][d4]
      const float4* Wk4 = (const float4*)(wk + (size_t)h * 8192);
      for (int ld4 = 0; ld4 < 32; ++ld4) {
        float4 zv = lds4[ld4 * 64 + (lane ^ (ld4 & 7))];
        int d4 = dc * 32 + ld4;
        const float4* wqr = Wq4 + (size_t)(w * 8) * 64 + d4;
        const float4* wkr = Wk4 + (size_t)(w * 8) * 64 + d4;
#pragma unroll
        for (int j = 0; j < 8; ++j) {
          float4 wv = wqr[j * 64];  // wave-uniform 16B broadcast
          qa[hh][j] = fmaf(wv.x, zv.x, fmaf(wv.y, zv.y,
                      fmaf(wv.z, zv.z, fmaf(wv.w, zv.w, qa[hh][j]))));
          float4 kv = wkr[j * 64];
          ka[hh][j] = fmaf(kv.x, zv.x, fmaf(kv.y, zv.y,
                      fmaf(kv.z, zv.z, fmaf(kv.w, zv.w, ka[hh][j]))));
        }
      }
    }
  }

  float* Qs = lds;         // [r][m] 32x64
  float* Ks = lds + 2048;  // [r][n] 32x64
  float lse = 0.f;
#pragma unroll
  for (int hh = 0; hh < 4; ++hh) {
    __syncthreads();  // previous readers of lds are done
#pragma unroll
    for (int j = 0; j < 8; ++j) {
      Qs[(w * 8 + j) * 64 + lane] = qa[hh][j];
      Ks[(w * 8 + j) * 64 + lane] = ka[hh][j];
    }
    __syncthreads();
    float av[16];
#pragma unroll
    for (int mm = 0; mm < 16; ++mm) av[mm] = 0.f;
    for (int rr = 0; rr < 32; ++rr) {
      float kv = Ks[rr * 64 + lane];
      const float* qrow = &Qs[rr * 64 + w * 16];
      float4 q0 = *(const float4*)(qrow + 0);
      float4 q1 = *(const float4*)(qrow + 4);
      float4 q2 = *(const float4*)(qrow + 8);
      float4 q3 = *(const float4*)(qrow + 12);
      av[0]  = fmaf(q0.x, kv, av[0]);  av[1]  = fmaf(q0.y, kv, av[1]);
      av[2]  = fmaf(q0.z, kv, av[2]);  av[3]  = fmaf(q0.w, kv, av[3]);
      av[4]  = fmaf(q1.x, kv, av[4]);  av[5]  = fmaf(q1.y, kv, av[5]);
      av[6]  = fmaf(q1.z, kv, av[6]);  av[7]  = fmaf(q1.w, kv, av[7]);
      av[8]  = fmaf(q2.x, kv, av[8]);  av[9]  = fmaf(q2.y, kv, av[9]);
      av[10] = fmaf(q2.z, kv, av[10]); av[11] = fmaf(q2.w, kv, av[11]);
      av[12] = fmaf(q3.x, kv, av[12]); av[13] = fmaf(q3.y, kv, av[13]);
      av[14] = fmaf(q3.z, kv, av[14]); av[15] = fmaf(q3.w, kv, av[15]);
    }
#pragma unroll
    for (int mm = 0; mm < 16; ++mm) {
      float v = GAMMA * av[mm];
      float mx = v;
#pragma unroll
      for (int off = 32; off; off >>= 1) mx = fmaxf(mx, __shfl_xor(mx, off, 64));
      float e = __expf(v - mx);
#pragma unroll
      for (int off = 32; off; off >>= 1) e += __shfl_xor(e, off, 64);
      lse += mx + __logf(e);
    }
  }
  if (lane == 0) red[w] = lse;
  __syncthreads();
  if (t == 0)
    atomicAdd(out + b, -(red[0] + red[1] + red[2] + red[3]) * (1.0f / GAMMA));
}

// ---------------------------------------------------------------------------
extern "C" void kernel_launch(void* const* d_in, const int* in_sizes, int n_in,
                              void* d_out, int out_size, void* d_ws,
                              size_t ws_size, hipStream_t stream) {
  (void)in_sizes; (void)n_in; (void)out_size; (void)d_ws; (void)ws_size;
  const float* x  = (const float*)d_in[0];
  const float* z  = (const float*)d_in[1];
  const float* ew = (const float*)d_in[2];
  const float* eb = (const float*)d_in[3];
  const float* vb = (const float*)d_in[4];
  const float* pb = (const float*)d_in[5];
  const float* mw = (const float*)d_in[6];
  const float* wq = (const float*)d_in[7];
  const float* wk = (const float*)d_in[8];
  float* out = (float*)d_out;

  k_xz  <<<1024, 256, 0, stream>>>(x, z, vb, eb, pb, out);  // writes out[b]
  k_enc <<<1024, 256, 0, stream>>>(x, z, ew, out);          // atomic -=
  k_mem <<<4096, 256, 0, stream>>>(z, mw, out);             // atomic -=
  k_attn<<<2048, 256, 0, stream>>>(z, wq, wk, out);         // atomic -=
}

// Round 4
// 1083.890 us; speedup vs baseline: 2.5486x; 1.7517x over previous
//
#include <hip/hip_runtime.h>

#define GAMMA 0.25f

// Shapes: B=1024, C=3, H=64, D=256, NP=64 (8x8 grid of 8x8 patches),
//         M=1024, NH=8, R=32, P=8.  All fp32.  out[b] = quad - coupling.

__device__ __forceinline__ float dot4(float4 a, float4 b) {
  return fmaf(a.x, b.x, fmaf(a.y, b.y, fmaf(a.z, b.z, a.w * b.w)));
}

__device__ __forceinline__ void fma4(float4& a, float s, float4 w) {
  a.x = fmaf(s, w.x, a.x); a.y = fmaf(s, w.y, a.y);
  a.z = fmaf(s, w.z, a.z); a.w = fmaf(s, w.w, a.w);
}

// 256-thread block sum; result valid on all threads.
__device__ __forceinline__ float block_sum_256(float v, float* tmp) {
#pragma unroll
  for (int off = 32; off; off >>= 1) v += __shfl_down(v, off, 64);
  int w = threadIdx.x >> 6;
  if ((threadIdx.x & 63) == 0) tmp[w] = v;
  __syncthreads();
  return tmp[0] + tmp[1] + tmp[2] + tmp[3];
}

// ---------------------------------------------------------------------------
// Kernel 1: quad_x + quad_z - phi_vis - phi_bias - phi_pos. Memory-bound.
// Sole non-atomic writer -> initializes out[b].
// ---------------------------------------------------------------------------
__global__ __launch_bounds__(256) void k_xz(const float* __restrict__ x,
                                            const float* __restrict__ z,
                                            const float* __restrict__ vb,
                                            const float* __restrict__ eb,
                                            const float* __restrict__ pb,
                                            float* __restrict__ out) {
  __shared__ float tmp[4];
  int b = blockIdx.x, t = threadIdx.x;
  const float4* xb = (const float4*)(x + (size_t)b * 12288);
  const float4* vb4 = (const float4*)vb;
  float s = 0.f;
  for (int i = t; i < 3072; i += 256) {
    float4 xv = xb[i];
    float4 bv = vb4[i];
    s += 0.5f * dot4(xv, xv) - dot4(bv, xv);
  }
  const float4* zb = (const float4*)(z + (size_t)b * 16384);
  const float4* pb4 = (const float4*)pb;
  const float4* eb4 = (const float4*)eb;
  for (int i = t; i < 4096; i += 256) {
    float4 zv = zb[i];
    float4 pv = pb4[i];
    float4 ev = eb4[i & 63];
    float4 c;
    c.x = pv.x + ev.x; c.y = pv.y + ev.y; c.z = pv.z + ev.z; c.w = pv.w + ev.w;
    s += 0.5f * dot4(zv, zv) - dot4(zv, c);
  }
  float r = block_sum_256(s, tmp);
  if (t == 0) out[b] = r;
}

// ---------------------------------------------------------------------------
// Kernel 2: phi_enc. One block per batch; x[b] staged in LDS (48 KB) so the
// inner loop is 1 global dwordx4 (w) + 64 LDS b128 broadcasts + 256 FMA.
// Thread t owns output channel d=t, acc over the 64 patches.
// ---------------------------------------------------------------------------
__global__ __launch_bounds__(256) void k_enc(const float* __restrict__ x,
                                             const float* __restrict__ z,
                                             const float* __restrict__ ew,
                                             float* __restrict__ out) {
  __shared__ float xs[12288];  // 48 KB: raw x[b] copy [c][64][64]
  __shared__ float tmp[4];
  int b = blockIdx.x, t = threadIdx.x;
  const float4* xb4 = (const float4*)(x + (size_t)b * 12288);
  for (int i = t; i < 3072; i += 256) ((float4*)xs)[i] = xb4[i];
  __syncthreads();

  float acc[64];
#pragma unroll
  for (int p = 0; p < 64; ++p) acc[p] = 0.f;

  // k = c*64 + i*8 + j over the 192 patch elements; k4 = k/4.
  for (int k4 = 0; k4 < 48; ++k4) {
    float4 wv = *(const float4*)(ew + (size_t)t * 192 + k4 * 4);
    int c = k4 >> 4;
    int ii = (k4 >> 1) & 7;
    int jh = (k4 & 1) * 4;
    const float* base = xs + c * 4096 + ii * 64 + jh;
#pragma unroll
    for (int p = 0; p < 64; ++p) {  // p = gi*8+gj
      float4 pv = *(const float4*)(base + (p >> 3) * 512 + (p & 7) * 8);
      acc[p] = fmaf(wv.x, pv.x,
               fmaf(wv.y, pv.y, fmaf(wv.z, pv.z, fmaf(wv.w, pv.w, acc[p]))));
    }
  }
  const float* zb = z + (size_t)b * 16384;
  float s = 0.f;
#pragma unroll
  for (int p = 0; p < 64; ++p) s += acc[p] * zb[p * 256 + t];
  float r = block_sum_256(s, tmp);
  if (t == 0) atomicAdd(out + b, -r);
}

// ---------------------------------------------------------------------------
// Kernel 3: phi_mem = sum relu(z @ mw)^2, fused. Block = (b, p-tile of 16).
// z-tile staged in LDS (16 KB); inner k4-loop: 4 coalesced w float4 loads +
// 16 LDS b128 broadcasts + 256 FMA. Thread t owns m = 4t..4t+3.
// ---------------------------------------------------------------------------
__global__ __launch_bounds__(256) void k_mem(const float* __restrict__ z,
                                             const float* __restrict__ mw,
                                             float* __restrict__ out) {
  __shared__ float zs[16 * 256];  // [p][k], 16 KB
  __shared__ float tmp[4];
  int b = blockIdx.x >> 2, pt = blockIdx.x & 3, t = threadIdx.x;
  const float4* zb4 = (const float4*)(z + (size_t)b * 16384 + pt * 4096);
  for (int i = t; i < 1024; i += 256) ((float4*)zs)[i] = zb4[i];
  __syncthreads();

  const float4* m4 = (const float4*)mw;  // [k*256 + t] -> mw[k*1024 + 4t..]
  float4 acc[16];
#pragma unroll
  for (int pp = 0; pp < 16; ++pp) acc[pp] = make_float4(0.f, 0.f, 0.f, 0.f);

#pragma unroll 2
  for (int k4 = 0; k4 < 64; ++k4) {
    float4 w0 = m4[(4 * k4 + 0) * 256 + t];
    float4 w1 = m4[(4 * k4 + 1) * 256 + t];
    float4 w2 = m4[(4 * k4 + 2) * 256 + t];
    float4 w3 = m4[(4 * k4 + 3) * 256 + t];
#pragma unroll
    for (int pp = 0; pp < 16; ++pp) {
      float4 zv = *(const float4*)&zs[pp * 256 + k4 * 4];
      fma4(acc[pp], zv.x, w0);
      fma4(acc[pp], zv.y, w1);
      fma4(acc[pp], zv.z, w2);
      fma4(acc[pp], zv.w, w3);
    }
  }
  float total = 0.f;
#pragma unroll
  for (int pp = 0; pp < 16; ++pp) {
    float r;
    r = fmaxf(acc[pp].x, 0.f); total = fmaf(r, r, total);
    r = fmaxf(acc[pp].y, 0.f); total = fmaf(r, r, total);
    r = fmaxf(acc[pp].z, 0.f); total = fmaf(r, r, total);
    r = fmaxf(acc[pp].w, 0.f); total = fmaf(r, r, total);
  }
  float r = block_sum_256(total, tmp);
  if (t == 0) atomicAdd(out + b, -r);
}

// ---------------------------------------------------------------------------
// Kernel 4: phi_att. Block = (b, half): 4 heads. Phase 1: z[b] staged in LDS
// d-major (two 32 KB chunks, XOR-swizzled), Q/K for 4 heads in registers.
// W loads: row base made provably wave-uniform via readfirstlane (-> scalar
// s_load path) and all 16 loads per ld4 hoisted into arrays so they pipeline
// as one latency batch instead of 16 serialized stalls (R3: VGPR=88 showed
// the compiler was NOT hoisting; each broadcast load stalled ~200cyc).
// Phase 2: A = Q^T K from LDS; logsumexp without max-pass (gamma*A bounded
// ~+-6 -> exp in [2.5e-3, 4e2], sum64 < 3e4: fp32-safe, identical math).
// ---------------------------------------------------------------------------
__global__ __launch_bounds__(256) void k_attn(const float* __restrict__ z,
                                              const float* __restrict__ wq,
                                              const float* __restrict__ wk,
                                              float* __restrict__ out) {
  __shared__ float lds[8192];  // 32 KB
  __shared__ float red[4];
  const int b = blockIdx.x >> 1, half = blockIdx.x & 1;
  const int t = threadIdx.x;
  const int lane = t & 63;  // p (phase 1) / n (phase 2)
  const int w = __builtin_amdgcn_readfirstlane(t >> 6);  // wave id, SGPR
  const float4* zb4 = (const float4*)(z + (size_t)b * 16384);

  float qa[4][8], ka[4][8];
#pragma unroll
  for (int hh = 0; hh < 4; ++hh)
#pragma unroll
    for (int j = 0; j < 8; ++j) { qa[hh][j] = 0.f; ka[hh][j] = 0.f; }

  float4* lds4 = (float4*)lds;
  for (int dc = 0; dc < 2; ++dc) {
    __syncthreads();
    for (int i = t; i < 2048; i += 256) {
      int p = i >> 5, ld4 = i & 31;
      lds4[ld4 * 64 + (p ^ (ld4 & 7))] = zb4[p * 64 + dc * 32 + ld4];
    }
    __syncthreads();
#pragma unroll
    for (int hh = 0; hh < 4; ++hh) {
      int h = half * 4 + hh;
      // wave-uniform row base: rows w*8..w*8+7 of W[h], d-chunk dc.
      const float* Wqb = wq + (size_t)h * 8192 + (size_t)(w * 8) * 256 + dc * 128;
      const float* Wkb = wk + (size_t)h * 8192 + (size_t)(w * 8) * 256 + dc * 128;
      for (int ld4 = 0; ld4 < 32; ++ld4) {
        float4 wv[8], kv[8];
#pragma unroll
        for (int j = 0; j < 8; ++j) {
          wv[j] = *(const float4*)(Wqb + j * 256 + ld4 * 4);
          kv[j] = *(const float4*)(Wkb + j * 256 + ld4 * 4);
        }
        float4 zv = lds4[ld4 * 64 + (lane ^ (ld4 & 7))];
#pragma unroll
        for (int j = 0; j < 8; ++j) {
          qa[hh][j] = fmaf(wv[j].x, zv.x, fmaf(wv[j].y, zv.y,
                      fmaf(wv[j].z, zv.z, fmaf(wv[j].w, zv.w, qa[hh][j]))));
          ka[hh][j] = fmaf(kv[j].x, zv.x, fmaf(kv[j].y, zv.y,
                      fmaf(kv[j].z, zv.z, fmaf(kv[j].w, zv.w, ka[hh][j]))));
        }
      }
    }
  }

  float* Qs = lds;         // [r][m] 32x64
  float* Ks = lds + 2048;  // [r][n] 32x64
  float lse = 0.f;
#pragma unroll
  for (int hh = 0; hh < 4; ++hh) {
    __syncthreads();  // previous readers of lds are done
#pragma unroll
    for (int j = 0; j < 8; ++j) {
      Qs[(w * 8 + j) * 64 + lane] = qa[hh][j];
      Ks[(w * 8 + j) * 64 + lane] = ka[hh][j];
    }
    __syncthreads();
    float av[16];
#pragma unroll
    for (int mm = 0; mm < 16; ++mm) av[mm] = 0.f;
    for (int rr = 0; rr < 32; ++rr) {
      float kv = Ks[rr * 64 + lane];
      const float* qrow = &Qs[rr * 64 + w * 16];
      float4 q0 = *(const float4*)(qrow + 0);
      float4 q1 = *(const float4*)(qrow + 4);
      float4 q2 = *(const float4*)(qrow + 8);
      float4 q3 = *(const float4*)(qrow + 12);
      av[0]  = fmaf(q0.x, kv, av[0]);  av[1]  = fmaf(q0.y, kv, av[1]);
      av[2]  = fmaf(q0.z, kv, av[2]);  av[3]  = fmaf(q0.w, kv, av[3]);
      av[4]  = fmaf(q1.x, kv, av[4]);  av[5]  = fmaf(q1.y, kv, av[5]);
      av[6]  = fmaf(q1.z, kv, av[6]);  av[7]  = fmaf(q1.w, kv, av[7]);
      av[8]  = fmaf(q2.x, kv, av[8]);  av[9]  = fmaf(q2.y, kv, av[9]);
      av[10] = fmaf(q2.z, kv, av[10]); av[11] = fmaf(q2.w, kv, av[11]);
      av[12] = fmaf(q3.x, kv, av[12]); av[13] = fmaf(q3.y, kv, av[13]);
      av[14] = fmaf(q3.z, kv, av[14]); av[15] = fmaf(q3.w, kv, av[15]);
    }
#pragma unroll
    for (int mm = 0; mm < 16; ++mm) {
      float e = __expf(GAMMA * av[mm]);
#pragma unroll
      for (int off = 32; off; off >>= 1) e += __shfl_xor(e, off, 64);
      lse += __logf(e);
    }
  }
  if (lane == 0) red[w] = lse;
  __syncthreads();
  if (t == 0)
    atomicAdd(out + b, -(red[0] + red[1] + red[2] + red[3]) * (1.0f / GAMMA));
}

// ---------------------------------------------------------------------------
extern "C" void kernel_launch(void* const* d_in, const int* in_sizes, int n_in,
                              void* d_out, int out_size, void* d_ws,
                              size_t ws_size, hipStream_t stream) {
  (void)in_sizes; (void)n_in; (void)out_size; (void)d_ws; (void)ws_size;
  const float* x  = (const float*)d_in[0];
  const float* z  = (const float*)d_in[1];
  const float* ew = (const float*)d_in[2];
  const float* eb = (const float*)d_in[3];
  const float* vb = (const float*)d_in[4];
  const float* pb = (const float*)d_in[5];
  const float* mw = (const float*)d_in[6];
  const float* wq = (const float*)d_in[7];
  const float* wk = (const float*)d_in[8];
  float* out = (float*)d_out;

  k_xz  <<<1024, 256, 0, stream>>>(x, z, vb, eb, pb, out);  // writes out[b]
  k_enc <<<1024, 256, 0, stream>>>(x, z, ew, out);          // atomic -=
  k_mem <<<4096, 256, 0, stream>>>(z, mw, out);             // atomic -=
  k_attn<<<2048, 256, 0, stream>>>(z, wq, wk, out);         // atomic -=
}

// Round 5
// 937.136 us; speedup vs baseline: 2.9476x; 1.1566x over previous
//
#include <hip/hip_runtime.h>
#include <hip/hip_bf16.h>

#define GAMMA 0.25f

// Shapes: B=1024, C=3, H=64, D=256, NP=64 (8x8 grid of 8x8 patches),
//         M=1024, NH=8, R=32, P=8.  fp32 in/out.  out[b] = quad - coupling.

typedef __attribute__((ext_vector_type(8))) short short8;  // 8 bf16 (4 VGPRs)
typedef __attribute__((ext_vector_type(4))) float f32x4;   // 4 fp32 acc

__device__ __forceinline__ float dot4(float4 a, float4 b) {
  return fmaf(a.x, b.x, fmaf(a.y, b.y, fmaf(a.z, b.z, a.w * b.w)));
}

__device__ __forceinline__ void fma4(float4& a, float s, float4 w) {
  a.x = fmaf(s, w.x, a.x); a.y = fmaf(s, w.y, a.y);
  a.z = fmaf(s, w.z, a.z); a.w = fmaf(s, w.w, a.w);
}

__device__ __forceinline__ ushort f2bf(float f) {
  __hip_bfloat16 h = __float2bfloat16(f);  // RNE
  return *reinterpret_cast<ushort*>(&h);
}

// 256-thread block sum; result valid on all threads.
__device__ __forceinline__ float block_sum_256(float v, float* tmp) {
#pragma unroll
  for (int off = 32; off; off >>= 1) v += __shfl_down(v, off, 64);
  int w = threadIdx.x >> 6;
  if ((threadIdx.x & 63) == 0) tmp[w] = v;
  __syncthreads();
  return tmp[0] + tmp[1] + tmp[2] + tmp[3];
}

// ---------------------------------------------------------------------------
// Kernel 1: quad_x + quad_z - phi_vis - phi_bias - phi_pos. Memory-bound.
// Sole non-atomic writer -> initializes out[b].
// ---------------------------------------------------------------------------
__global__ __launch_bounds__(256) void k_xz(const float* __restrict__ x,
                                            const float* __restrict__ z,
                                            const float* __restrict__ vb,
                                            const float* __restrict__ eb,
                                            const float* __restrict__ pb,
                                            float* __restrict__ out) {
  __shared__ float tmp[4];
  int b = blockIdx.x, t = threadIdx.x;
  const float4* xb = (const float4*)(x + (size_t)b * 12288);
  const float4* vb4 = (const float4*)vb;
  float s = 0.f;
  for (int i = t; i < 3072; i += 256) {
    float4 xv = xb[i];
    float4 bv = vb4[i];
    s += 0.5f * dot4(xv, xv) - dot4(bv, xv);
  }
  const float4* zb = (const float4*)(z + (size_t)b * 16384);
  const float4* pb4 = (const float4*)pb;
  const float4* eb4 = (const float4*)eb;
  for (int i = t; i < 4096; i += 256) {
    float4 zv = zb[i];
    float4 pv = pb4[i];
    float4 ev = eb4[i & 63];
    float4 c;
    c.x = pv.x + ev.x; c.y = pv.y + ev.y; c.z = pv.z + ev.z; c.w = pv.w + ev.w;
    s += 0.5f * dot4(zv, zv) - dot4(zv, c);
  }
  float r = block_sum_256(s, tmp);
  if (t == 0) out[b] = r;
}

// ---------------------------------------------------------------------------
// Kernel 2: phi_enc. One block per batch; x[b] staged in LDS (48 KB).
// ---------------------------------------------------------------------------
__global__ __launch_bounds__(256) void k_enc(const float* __restrict__ x,
                                             const float* __restrict__ z,
                                             const float* __restrict__ ew,
                                             float* __restrict__ out) {
  __shared__ float xs[12288];
  __shared__ float tmp[4];
  int b = blockIdx.x, t = threadIdx.x;
  const float4* xb4 = (const float4*)(x + (size_t)b * 12288);
  for (int i = t; i < 3072; i += 256) ((float4*)xs)[i] = xb4[i];
  __syncthreads();

  float acc[64];
#pragma unroll
  for (int p = 0; p < 64; ++p) acc[p] = 0.f;

  for (int k4 = 0; k4 < 48; ++k4) {
    float4 wv = *(const float4*)(ew + (size_t)t * 192 + k4 * 4);
    int c = k4 >> 4;
    int ii = (k4 >> 1) & 7;
    int jh = (k4 & 1) * 4;
    const float* base = xs + c * 4096 + ii * 64 + jh;
#pragma unroll
    for (int p = 0; p < 64; ++p) {
      float4 pv = *(const float4*)(base + (p >> 3) * 512 + (p & 7) * 8);
      acc[p] = fmaf(wv.x, pv.x,
               fmaf(wv.y, pv.y, fmaf(wv.z, pv.z, fmaf(wv.w, pv.w, acc[p]))));
    }
  }
  const float* zb = z + (size_t)b * 16384;
  float s = 0.f;
#pragma unroll
  for (int p = 0; p < 64; ++p) s += acc[p] * zb[p * 256 + t];
  float r = block_sum_256(s, tmp);
  if (t == 0) atomicAdd(out + b, -r);
}

// ---------------------------------------------------------------------------
// bf16 conversions for the MFMA path (into d_ws).
// k_cvt: z (16.8M fp32) -> bf16, elementwise.  k_cvt_mw: mw[k][m] -> mt[m][k].
// ---------------------------------------------------------------------------
__global__ __launch_bounds__(256) void k_cvt(const float4* __restrict__ z4,
                                             ushort4* __restrict__ o4) {
  int i = blockIdx.x * 256 + threadIdx.x;  // 16384 blocks -> 4.19M float4s
  float4 v = z4[i];
  ushort4 o;
  o.x = f2bf(v.x); o.y = f2bf(v.y); o.z = f2bf(v.z); o.w = f2bf(v.w);
  o4[i] = o;
}

__global__ __launch_bounds__(256) void k_cvt_mw(const float* __restrict__ mw,
                                                ushort* __restrict__ mt) {
  int j = blockIdx.x * 256 + threadIdx.x;  // 128 blocks -> 32768 threads
  int m = j >> 5, k8 = j & 31;
  ushort tmp[8];
#pragma unroll
  for (int i = 0; i < 8; ++i) tmp[i] = f2bf(mw[(size_t)(k8 * 8 + i) * 1024 + m]);
  ushort4 a, c;
  a.x = tmp[0]; a.y = tmp[1]; a.z = tmp[2]; a.w = tmp[3];
  c.x = tmp[4]; c.y = tmp[5]; c.z = tmp[6]; c.w = tmp[7];
  *(ushort4*)(mt + (size_t)m * 256 + k8 * 8) = a;
  *(ushort4*)(mt + (size_t)m * 256 + k8 * 8 + 4) = c;
}

// ---------------------------------------------------------------------------
// Kernel 3 (MFMA): phi_mem = sum relu(z @ mw)^2 via bf16 16x16x32 MFMA.
// Block = (b, 256-col tile); wave w owns z-rows w*16..+16 and 16 col-tiles.
// K=256 in 8 steps. A-frag: lane l -> z[row=base+(l&15)][k0+(l>>4)*8..+8]
// (16B contig); B-frag from mt[m][k] likewise (B^T layout). relu^2-sum over
// ALL acc elements -> C/D lane mapping is irrelevant to correctness.
// ---------------------------------------------------------------------------
__global__ __launch_bounds__(256) void k_mem_mfma(const ushort* __restrict__ zb,
                                                  const ushort* __restrict__ mt,
                                                  float* __restrict__ out) {
  __shared__ float tmp[4];
  const int t = threadIdx.x, l = t & 63, w = t >> 6;
  const int b = blockIdx.x >> 2, ct = blockIdx.x & 3;
  const ushort* Abase = zb + ((size_t)b * 64 + w * 16 + (l & 15)) * 256 + (l >> 4) * 8;
  const ushort* Bbase = mt + ((size_t)ct * 256 + (l & 15)) * 256 + (l >> 4) * 8;

  f32x4 acc[16];
#pragma unroll
  for (int c = 0; c < 16; ++c) acc[c] = f32x4{0.f, 0.f, 0.f, 0.f};

  for (int ks = 0; ks < 8; ++ks) {
    short8 a = *(const short8*)(Abase + ks * 32);
#pragma unroll
    for (int c = 0; c < 16; ++c) {
      short8 bf = *(const short8*)(Bbase + (size_t)c * 4096 + ks * 32);
      acc[c] = __builtin_amdgcn_mfma_f32_16x16x32_bf16(a, bf, acc[c], 0, 0, 0);
    }
  }
  float s = 0.f;
#pragma unroll
  for (int c = 0; c < 16; ++c) {
#pragma unroll
    for (int e = 0; e < 4; ++e) {
      float r = fmaxf(acc[c][e], 0.f);
      s = fmaf(r, r, s);
    }
  }
  float r = block_sum_256(s, tmp);
  if (t == 0) atomicAdd(out + b, -r);
}

// ---------------------------------------------------------------------------
// Kernel 3 (fp32 fallback, used only if ws_size too small).
// ---------------------------------------------------------------------------
__global__ __launch_bounds__(256) void k_mem(const float* __restrict__ z,
                                             const float* __restrict__ mw,
                                             float* __restrict__ out) {
  __shared__ float zs[16 * 256];
  __shared__ float tmp[4];
  int b = blockIdx.x >> 2, pt = blockIdx.x & 3, t = threadIdx.x;
  const float4* zb4 = (const float4*)(z + (size_t)b * 16384 + pt * 4096);
  for (int i = t; i < 1024; i += 256) ((float4*)zs)[i] = zb4[i];
  __syncthreads();

  const float4* m4 = (const float4*)mw;
  float4 acc[16];
#pragma unroll
  for (int pp = 0; pp < 16; ++pp) acc[pp] = make_float4(0.f, 0.f, 0.f, 0.f);

#pragma unroll 2
  for (int k4 = 0; k4 < 64; ++k4) {
    float4 w0 = m4[(4 * k4 + 0) * 256 + t];
    float4 w1 = m4[(4 * k4 + 1) * 256 + t];
    float4 w2 = m4[(4 * k4 + 2) * 256 + t];
    float4 w3 = m4[(4 * k4 + 3) * 256 + t];
#pragma unroll
    for (int pp = 0; pp < 16; ++pp) {
      float4 zv = *(const float4*)&zs[pp * 256 + k4 * 4];
      fma4(acc[pp], zv.x, w0);
      fma4(acc[pp], zv.y, w1);
      fma4(acc[pp], zv.z, w2);
      fma4(acc[pp], zv.w, w3);
    }
  }
  float total = 0.f;
#pragma unroll
  for (int pp = 0; pp < 16; ++pp) {
    float r;
    r = fmaxf(acc[pp].x, 0.f); total = fmaf(r, r, total);
    r = fmaxf(acc[pp].y, 0.f); total = fmaf(r, r, total);
    r = fmaxf(acc[pp].z, 0.f); total = fmaf(r, r, total);
    r = fmaxf(acc[pp].w, 0.f); total = fmaf(r, r, total);
  }
  float r = block_sum_256(total, tmp);
  if (t == 0) atomicAdd(out + b, -r);
}

// ---------------------------------------------------------------------------
// Kernel 4: phi_att (unchanged from R4; 417 us, next target after bf16 probe).
// ---------------------------------------------------------------------------
__global__ __launch_bounds__(256) void k_attn(const float* __restrict__ z,
                                              const float* __restrict__ wq,
                                              const float* __restrict__ wk,
                                              float* __restrict__ out) {
  __shared__ float lds[8192];
  __shared__ float red[4];
  const int b = blockIdx.x >> 1, half = blockIdx.x & 1;
  const int t = threadIdx.x;
  const int lane = t & 63;
  const int w = __builtin_amdgcn_readfirstlane(t >> 6);
  const float4* zb4 = (const float4*)(z + (size_t)b * 16384);

  float qa[4][8], ka[4][8];
#pragma unroll
  for (int hh = 0; hh < 4; ++hh)
#pragma unroll
    for (int j = 0; j < 8; ++j) { qa[hh][j] = 0.f; ka[hh][j] = 0.f; }

  float4* lds4 = (float4*)lds;
  for (int dc = 0; dc < 2; ++dc) {
    __syncthreads();
    for (int i = t; i < 2048; i += 256) {
      int p = i >> 5, ld4 = i & 31;
      lds4[ld4 * 64 + (p ^ (ld4 & 7))] = zb4[p * 64 + dc * 32 + ld4];
    }
    __syncthreads();
#pragma unroll
    for (int hh = 0; hh < 4; ++hh) {
      int h = half * 4 + hh;
      const float* Wqb = wq + (size_t)h * 8192 + (size_t)(w * 8) * 256 + dc * 128;
      const float* Wkb = wk + (size_t)h * 8192 + (size_t)(w * 8) * 256 + dc * 128;
      for (int ld4 = 0; ld4 < 32; ++ld4) {
        float4 wv[8], kv[8];
#pragma unroll
        for (int j = 0; j < 8; ++j) {
          wv[j] = *(const float4*)(Wqb + j * 256 + ld4 * 4);
          kv[j] = *(const float4*)(Wkb + j * 256 + ld4 * 4);
        }
        float4 zv = lds4[ld4 * 64 + (lane ^ (ld4 & 7))];
#pragma unroll
        for (int j = 0; j < 8; ++j) {
          qa[hh][j] = fmaf(wv[j].x, zv.x, fmaf(wv[j].y, zv.y,
                      fmaf(wv[j].z, zv.z, fmaf(wv[j].w, zv.w, qa[hh][j]))));
          ka[hh][j] = fmaf(kv[j].x, zv.x, fmaf(kv[j].y, zv.y,
                      fmaf(kv[j].z, zv.z, fmaf(kv[j].w, zv.w, ka[hh][j]))));
        }
      }
    }
  }

  float* Qs = lds;
  float* Ks = lds + 2048;
  float lse = 0.f;
#pragma unroll
  for (int hh = 0; hh < 4; ++hh) {
    __syncthreads();
#pragma unroll
    for (int j = 0; j < 8; ++j) {
      Qs[(w * 8 + j) * 64 + lane] = qa[hh][j];
      Ks[(w * 8 + j) * 64 + lane] = ka[hh][j];
    }
    __syncthreads();
    float av[16];
#pragma unroll
    for (int mm = 0; mm < 16; ++mm) av[mm] = 0.f;
    for (int rr = 0; rr < 32; ++rr) {
      float kv = Ks[rr * 64 + lane];
      const float* qrow = &Qs[rr * 64 + w * 16];
      float4 q0 = *(const float4*)(qrow + 0);
      float4 q1 = *(const float4*)(qrow + 4);
      float4 q2 = *(const float4*)(qrow + 8);
      float4 q3 = *(const float4*)(qrow + 12);
      av[0]  = fmaf(q0.x, kv, av[0]);  av[1]  = fmaf(q0.y, kv, av[1]);
      av[2]  = fmaf(q0.z, kv, av[2]);  av[3]  = fmaf(q0.w, kv, av[3]);
      av[4]  = fmaf(q1.x, kv, av[4]);  av[5]  = fmaf(q1.y, kv, av[5]);
      av[6]  = fmaf(q1.z, kv, av[6]);  av[7]  = fmaf(q1.w, kv, av[7]);
      av[8]  = fmaf(q2.x, kv, av[8]);  av[9]  = fmaf(q2.y, kv, av[9]);
      av[10] = fmaf(q2.z, kv, av[10]); av[11] = fmaf(q2.w, kv, av[11]);
      av[12] = fmaf(q3.x, kv, av[12]); av[13] = fmaf(q3.y, kv, av[13]);
      av[14] = fmaf(q3.z, kv, av[14]); av[15] = fmaf(q3.w, kv, av[15]);
    }
#pragma unroll
    for (int mm = 0; mm < 16; ++mm) {
      float e = __expf(GAMMA * av[mm]);
#pragma unroll
      for (int off = 32; off; off >>= 1) e += __shfl_xor(e, off, 64);
      lse += __logf(e);
    }
  }
  if (lane == 0) red[w] = lse;
  __syncthreads();
  if (t == 0)
    atomicAdd(out + b, -(red[0] + red[1] + red[2] + red[3]) * (1.0f / GAMMA));
}

// ---------------------------------------------------------------------------
extern "C" void kernel_launch(void* const* d_in, const int* in_sizes, int n_in,
                              void* d_out, int out_size, void* d_ws,
                              size_t ws_size, hipStream_t stream) {
  (void)in_sizes; (void)n_in; (void)out_size;
  const float* x  = (const float*)d_in[0];
  const float* z  = (const float*)d_in[1];
  const float* ew = (const float*)d_in[2];
  const float* eb = (const float*)d_in[3];
  const float* vb = (const float*)d_in[4];
  const float* pb = (const float*)d_in[5];
  const float* mw = (const float*)d_in[6];
  const float* wq = (const float*)d_in[7];
  const float* wk = (const float*)d_in[8];
  float* out = (float*)d_out;

  const size_t Z_BF16_BYTES = (size_t)1024 * 64 * 256 * 2;  // 33.5 MB
  const size_t MT_BF16_BYTES = (size_t)1024 * 256 * 2;      // 0.5 MB
  bool use_mfma = ws_size >= Z_BF16_BYTES + MT_BF16_BYTES;

  k_xz  <<<1024, 256, 0, stream>>>(x, z, vb, eb, pb, out);  // writes out[b]
  k_enc <<<1024, 256, 0, stream>>>(x, z, ew, out);          // atomic -=
  if (use_mfma) {
    ushort* zb16 = (ushort*)d_ws;
    ushort* mt16 = (ushort*)((char*)d_ws + Z_BF16_BYTES);
    k_cvt    <<<16384, 256, 0, stream>>>((const float4*)z, (ushort4*)zb16);
    k_cvt_mw <<<128, 256, 0, stream>>>(mw, mt16);
    k_mem_mfma<<<4096, 256, 0, stream>>>(zb16, mt16, out);  // atomic -=
  } else {
    k_mem <<<4096, 256, 0, stream>>>(z, mw, out);           // atomic -=
  }
  k_attn<<<2048, 256, 0, stream>>>(z, wq, wk, out);         // atomic -=
}

// Round 6
// 730.550 us; speedup vs baseline: 3.7812x; 1.2828x over previous
//
#include <hip/hip_runtime.h>
#include <hip/hip_bf16.h>

#define GAMMA 0.25f

// Shapes: B=1024, C=3, H=64, D=256, NP=64 (8x8 grid of 8x8 patches),
//         M=1024, NH=8, R=32, P=8.  fp32 in/out.  out[b] = quad - coupling.

typedef __attribute__((ext_vector_type(8))) short short8;  // 8 bf16 (4 VGPRs)
typedef __attribute__((ext_vector_type(4))) float f32x4;   // 4 fp32 acc

__device__ __forceinline__ float dot4(float4 a, float4 b) {
  return fmaf(a.x, b.x, fmaf(a.y, b.y, fmaf(a.z, b.z, a.w * b.w)));
}

__device__ __forceinline__ void fma4(float4& a, float s, float4 w) {
  a.x = fmaf(s, w.x, a.x); a.y = fmaf(s, w.y, a.y);
  a.z = fmaf(s, w.z, a.z); a.w = fmaf(s, w.w, a.w);
}

__device__ __forceinline__ ushort f2bf(float f) {
  __hip_bfloat16 h = __float2bfloat16(f);  // RNE
  return *reinterpret_cast<ushort*>(&h);
}

// 256-thread block sum; result valid on all threads.
__device__ __forceinline__ float block_sum_256(float v, float* tmp) {
#pragma unroll
  for (int off = 32; off; off >>= 1) v += __shfl_down(v, off, 64);
  int w = threadIdx.x >> 6;
  if ((threadIdx.x & 63) == 0) tmp[w] = v;
  __syncthreads();
  return tmp[0] + tmp[1] + tmp[2] + tmp[3];
}

// ---------------------------------------------------------------------------
// Kernel 1: quad_x + quad_z - phi_vis - phi_bias - phi_pos. Memory-bound.
// Sole non-atomic writer -> initializes out[b].
// ---------------------------------------------------------------------------
__global__ __launch_bounds__(256) void k_xz(const float* __restrict__ x,
                                            const float* __restrict__ z,
                                            const float* __restrict__ vb,
                                            const float* __restrict__ eb,
                                            const float* __restrict__ pb,
                                            float* __restrict__ out) {
  __shared__ float tmp[4];
  int b = blockIdx.x, t = threadIdx.x;
  const float4* xb = (const float4*)(x + (size_t)b * 12288);
  const float4* vb4 = (const float4*)vb;
  float s = 0.f;
  for (int i = t; i < 3072; i += 256) {
    float4 xv = xb[i];
    float4 bv = vb4[i];
    s += 0.5f * dot4(xv, xv) - dot4(bv, xv);
  }
  const float4* zb = (const float4*)(z + (size_t)b * 16384);
  const float4* pb4 = (const float4*)pb;
  const float4* eb4 = (const float4*)eb;
  for (int i = t; i < 4096; i += 256) {
    float4 zv = zb[i];
    float4 pv = pb4[i];
    float4 ev = eb4[i & 63];
    float4 c;
    c.x = pv.x + ev.x; c.y = pv.y + ev.y; c.z = pv.z + ev.z; c.w = pv.w + ev.w;
    s += 0.5f * dot4(zv, zv) - dot4(zv, c);
  }
  float r = block_sum_256(s, tmp);
  if (t == 0) out[b] = r;
}

// ---------------------------------------------------------------------------
// Kernel 2: phi_enc. One block per batch; x[b] staged in LDS (48 KB).
// ---------------------------------------------------------------------------
__global__ __launch_bounds__(256) void k_enc(const float* __restrict__ x,
                                             const float* __restrict__ z,
                                             const float* __restrict__ ew,
                                             float* __restrict__ out) {
  __shared__ float xs[12288];
  __shared__ float tmp[4];
  int b = blockIdx.x, t = threadIdx.x;
  const float4* xb4 = (const float4*)(x + (size_t)b * 12288);
  for (int i = t; i < 3072; i += 256) ((float4*)xs)[i] = xb4[i];
  __syncthreads();

  float acc[64];
#pragma unroll
  for (int p = 0; p < 64; ++p) acc[p] = 0.f;

  for (int k4 = 0; k4 < 48; ++k4) {
    float4 wv = *(const float4*)(ew + (size_t)t * 192 + k4 * 4);
    int c = k4 >> 4;
    int ii = (k4 >> 1) & 7;
    int jh = (k4 & 1) * 4;
    const float* base = xs + c * 4096 + ii * 64 + jh;
#pragma unroll
    for (int p = 0; p < 64; ++p) {
      float4 pv = *(const float4*)(base + (p >> 3) * 512 + (p & 7) * 8);
      acc[p] = fmaf(wv.x, pv.x,
               fmaf(wv.y, pv.y, fmaf(wv.z, pv.z, fmaf(wv.w, pv.w, acc[p]))));
    }
  }
  const float* zb = z + (size_t)b * 16384;
  float s = 0.f;
#pragma unroll
  for (int p = 0; p < 64; ++p) s += acc[p] * zb[p * 256 + t];
  float r = block_sum_256(s, tmp);
  if (t == 0) atomicAdd(out + b, -r);
}

// ---------------------------------------------------------------------------
// bf16 conversions (into d_ws).
// k_cvt: generic fp32 -> bf16 (grid sized by caller, 1 float4/thread).
// k_cvt_mw: mw[k][m] -> mt[m][k] transposed bf16.
// ---------------------------------------------------------------------------
__global__ __launch_bounds__(256) void k_cvt(const float4* __restrict__ z4,
                                             ushort4* __restrict__ o4) {
  int i = blockIdx.x * 256 + threadIdx.x;
  float4 v = z4[i];
  ushort4 o;
  o.x = f2bf(v.x); o.y = f2bf(v.y); o.z = f2bf(v.z); o.w = f2bf(v.w);
  o4[i] = o;
}

__global__ __launch_bounds__(256) void k_cvt_mw(const float* __restrict__ mw,
                                                ushort* __restrict__ mt) {
  int j = blockIdx.x * 256 + threadIdx.x;  // 128 blocks -> 32768 threads
  int m = j >> 5, k8 = j & 31;
  ushort tmp[8];
#pragma unroll
  for (int i = 0; i < 8; ++i) tmp[i] = f2bf(mw[(size_t)(k8 * 8 + i) * 1024 + m]);
  ushort4 a, c;
  a.x = tmp[0]; a.y = tmp[1]; a.z = tmp[2]; a.w = tmp[3];
  c.x = tmp[4]; c.y = tmp[5]; c.z = tmp[6]; c.w = tmp[7];
  *(ushort4*)(mt + (size_t)m * 256 + k8 * 8) = a;
  *(ushort4*)(mt + (size_t)m * 256 + k8 * 8 + 4) = c;
}

// ---------------------------------------------------------------------------
// Kernel 3 (MFMA): phi_mem = sum relu(z @ mw)^2 via bf16 16x16x32 MFMA.
// (validated R5: absmax 64 within tolerance)
// ---------------------------------------------------------------------------
__global__ __launch_bounds__(256) void k_mem_mfma(const ushort* __restrict__ zb,
                                                  const ushort* __restrict__ mt,
                                                  float* __restrict__ out) {
  __shared__ float tmp[4];
  const int t = threadIdx.x, l = t & 63, w = t >> 6;
  const int b = blockIdx.x >> 2, ct = blockIdx.x & 3;
  const ushort* Abase = zb + ((size_t)b * 64 + w * 16 + (l & 15)) * 256 + (l >> 4) * 8;
  const ushort* Bbase = mt + ((size_t)ct * 256 + (l & 15)) * 256 + (l >> 4) * 8;

  f32x4 acc[16];
#pragma unroll
  for (int c = 0; c < 16; ++c) acc[c] = f32x4{0.f, 0.f, 0.f, 0.f};

  for (int ks = 0; ks < 8; ++ks) {
    short8 a = *(const short8*)(Abase + ks * 32);
#pragma unroll
    for (int c = 0; c < 16; ++c) {
      short8 bf = *(const short8*)(Bbase + (size_t)c * 4096 + ks * 32);
      acc[c] = __builtin_amdgcn_mfma_f32_16x16x32_bf16(a, bf, acc[c], 0, 0, 0);
    }
  }
  float s = 0.f;
#pragma unroll
  for (int c = 0; c < 16; ++c) {
#pragma unroll
    for (int e = 0; e < 4; ++e) {
      float r = fmaxf(acc[c][e], 0.f);
      s = fmaf(r, r, s);
    }
  }
  float r = block_sum_256(s, tmp);
  if (t == 0) atomicAdd(out + b, -r);
}

// ---------------------------------------------------------------------------
// Kernel 4 (MFMA): phi_att. One block per b, 4 waves.
// Phase 1: Q/K = z @ W^T per head via 16x16x32 MFMA (M=64 patches: wave w owns
// m-tile w; N=32 r: 2 n-tiles; K=256: 8 steps). A-frags from zb16 (global,
// loaded once, reused across 8 heads + Q/K); B-frags from bf16 W (global,
// L2-hot across all blocks). D (C-layout: row=(l>>4)*4+reg, col=l&15, verified
// m89/m91) -> bf16 -> LDS [m][r] stride 40 (16B-aligned b128 reads).
// Phase 2: A-tile = Q_tile @ K_tile^T in ONE K=32 MFMA; lse = exp over 4
// n-tiles in regs + 4 shfl_xor over the 16-lane col group + 1 log per row.
// Wave-private phase-1 rows -> single __syncthreads.
// ---------------------------------------------------------------------------
__global__ __launch_bounds__(256) void k_attn_mfma(const ushort* __restrict__ zb,
                                                   const ushort* __restrict__ wq16,
                                                   const ushort* __restrict__ wk16,
                                                   float* __restrict__ out) {
  __shared__ ushort Qb[8 * 2560];  // [h][m][r], row stride 40 halfwords
  __shared__ ushort Kb[8 * 2560];  // [h][n][r]
  __shared__ float tmp[4];
  const int t = threadIdx.x, l = t & 63, w = t >> 6;
  const int b = blockIdx.x;
  const int q = l >> 4, m = l & 15;

  // A-fragments of z[b] for m-tile w: reused across all heads and Q/K.
  const ushort* Az = zb + ((size_t)b * 64 + 16 * w + m) * 256 + q * 8;
  short8 a[8];
#pragma unroll
  for (int ks = 0; ks < 8; ++ks) a[ks] = *(const short8*)(Az + ks * 32);

  for (int h = 0; h < 8; ++h) {
    f32x4 accq0 = f32x4{0.f, 0.f, 0.f, 0.f}, accq1 = accq0;
    f32x4 acck0 = accq0, acck1 = accq0;
    const ushort* Bq = wq16 + (size_t)h * 8192 + (size_t)m * 256 + q * 8;
    const ushort* Bk = wk16 + (size_t)h * 8192 + (size_t)m * 256 + q * 8;
#pragma unroll
    for (int ks = 0; ks < 8; ++ks) {
      short8 bq0 = *(const short8*)(Bq + ks * 32);
      short8 bq1 = *(const short8*)(Bq + 16 * 256 + ks * 32);
      short8 bk0 = *(const short8*)(Bk + ks * 32);
      short8 bk1 = *(const short8*)(Bk + 16 * 256 + ks * 32);
      accq0 = __builtin_amdgcn_mfma_f32_16x16x32_bf16(a[ks], bq0, accq0, 0, 0, 0);
      accq1 = __builtin_amdgcn_mfma_f32_16x16x32_bf16(a[ks], bq1, accq1, 0, 0, 0);
      acck0 = __builtin_amdgcn_mfma_f32_16x16x32_bf16(a[ks], bk0, acck0, 0, 0, 0);
      acck1 = __builtin_amdgcn_mfma_f32_16x16x32_bf16(a[ks], bk1, acck1, 0, 0, 0);
    }
    // D -> bf16 -> LDS. row(patch) = 16w + 4q + reg, col(r) = 16nt + m.
    int rowbase = h * 2560 + (16 * w + 4 * q) * 40;
#pragma unroll
    for (int reg = 0; reg < 4; ++reg) {
      Qb[rowbase + reg * 40 + m]      = f2bf(accq0[reg]);
      Qb[rowbase + reg * 40 + 16 + m] = f2bf(accq1[reg]);
      Kb[rowbase + reg * 40 + m]      = f2bf(acck0[reg]);
      Kb[rowbase + reg * 40 + 16 + m] = f2bf(acck1[reg]);
    }
  }
  __syncthreads();

  float part = 0.f;
#pragma unroll
  for (int h = 0; h < 8; ++h) {
    // A-frag: Q rows 16w+m (this wave's m-tile), k = r = q*8..q*8+7.
    short8 qa = *(const short8*)&Qb[h * 2560 + (16 * w + m) * 40 + q * 8];
    f32x4 acc[4];
#pragma unroll
    for (int nt = 0; nt < 4; ++nt) {
      short8 kb = *(const short8*)&Kb[h * 2560 + (16 * nt + m) * 40 + q * 8];
      acc[nt] = __builtin_amdgcn_mfma_f32_16x16x32_bf16(
          qa, kb, f32x4{0.f, 0.f, 0.f, 0.f}, 0, 0, 0);
    }
#pragma unroll
    for (int reg = 0; reg < 4; ++reg) {
      float e = __expf(GAMMA * acc[0][reg]) + __expf(GAMMA * acc[1][reg]) +
                __expf(GAMMA * acc[2][reg]) + __expf(GAMMA * acc[3][reg]);
      e += __shfl_xor(e, 1, 64);
      e += __shfl_xor(e, 2, 64);
      e += __shfl_xor(e, 4, 64);
      e += __shfl_xor(e, 8, 64);
      part += (m == 0) ? __logf(e) : 0.f;  // one log per row m=16w+4q+reg
    }
  }
  float tot = block_sum_256(part, tmp);
  if (t == 0) atomicAdd(out + b, -tot * (1.0f / GAMMA));
}

// ---------------------------------------------------------------------------
// fp32 fallbacks (used only if ws_size too small).
// ---------------------------------------------------------------------------
__global__ __launch_bounds__(256) void k_mem(const float* __restrict__ z,
                                             const float* __restrict__ mw,
                                             float* __restrict__ out) {
  __shared__ float zs[16 * 256];
  __shared__ float tmp[4];
  int b = blockIdx.x >> 2, pt = blockIdx.x & 3, t = threadIdx.x;
  const float4* zb4 = (const float4*)(z + (size_t)b * 16384 + pt * 4096);
  for (int i = t; i < 1024; i += 256) ((float4*)zs)[i] = zb4[i];
  __syncthreads();

  const float4* m4 = (const float4*)mw;
  float4 acc[16];
#pragma unroll
  for (int pp = 0; pp < 16; ++pp) acc[pp] = make_float4(0.f, 0.f, 0.f, 0.f);

#pragma unroll 2
  for (int k4 = 0; k4 < 64; ++k4) {
    float4 w0 = m4[(4 * k4 + 0) * 256 + t];
    float4 w1 = m4[(4 * k4 + 1) * 256 + t];
    float4 w2 = m4[(4 * k4 + 2) * 256 + t];
    float4 w3 = m4[(4 * k4 + 3) * 256 + t];
#pragma unroll
    for (int pp = 0; pp < 16; ++pp) {
      float4 zv = *(const float4*)&zs[pp * 256 + k4 * 4];
      fma4(acc[pp], zv.x, w0);
      fma4(acc[pp], zv.y, w1);
      fma4(acc[pp], zv.z, w2);
      fma4(acc[pp], zv.w, w3);
    }
  }
  float total = 0.f;
#pragma unroll
  for (int pp = 0; pp < 16; ++pp) {
    float r;
    r = fmaxf(acc[pp].x, 0.f); total = fmaf(r, r, total);
    r = fmaxf(acc[pp].y, 0.f); total = fmaf(r, r, total);
    r = fmaxf(acc[pp].z, 0.f); total = fmaf(r, r, total);
    r = fmaxf(acc[pp].w, 0.f); total = fmaf(r, r, total);
  }
  float r = block_sum_256(total, tmp);
  if (t == 0) atomicAdd(out + b, -r);
}

__global__ __launch_bounds__(256) void k_attn(const float* __restrict__ z,
                                              const float* __restrict__ wq,
                                              const float* __restrict__ wk,
                                              float* __restrict__ out) {
  __shared__ float lds[8192];
  __shared__ float red[4];
  const int b = blockIdx.x >> 1, half = blockIdx.x & 1;
  const int t = threadIdx.x;
  const int lane = t & 63;
  const int w = __builtin_amdgcn_readfirstlane(t >> 6);
  const float4* zb4 = (const float4*)(z + (size_t)b * 16384);

  float qa[4][8], ka[4][8];
#pragma unroll
  for (int hh = 0; hh < 4; ++hh)
#pragma unroll
    for (int j = 0; j < 8; ++j) { qa[hh][j] = 0.f; ka[hh][j] = 0.f; }

  float4* lds4 = (float4*)lds;
  for (int dc = 0; dc < 2; ++dc) {
    __syncthreads();
    for (int i = t; i < 2048; i += 256) {
      int p = i >> 5, ld4 = i & 31;
      lds4[ld4 * 64 + (p ^ (ld4 & 7))] = zb4[p * 64 + dc * 32 + ld4];
    }
    __syncthreads();
#pragma unroll
    for (int hh = 0; hh < 4; ++hh) {
      int h = half * 4 + hh;
      const float* Wqb = wq + (size_t)h * 8192 + (size_t)(w * 8) * 256 + dc * 128;
      const float* Wkb = wk + (size_t)h * 8192 + (size_t)(w * 8) * 256 + dc * 128;
      for (int ld4 = 0; ld4 < 32; ++ld4) {
        float4 wv[8], kv[8];
#pragma unroll
        for (int j = 0; j < 8; ++j) {
          wv[j] = *(const float4*)(Wqb + j * 256 + ld4 * 4);
          kv[j] = *(const float4*)(Wkb + j * 256 + ld4 * 4);
        }
        float4 zv = lds4[ld4 * 64 + (lane ^ (ld4 & 7))];
#pragma unroll
        for (int j = 0; j < 8; ++j) {
          qa[hh][j] = fmaf(wv[j].x, zv.x, fmaf(wv[j].y, zv.y,
                      fmaf(wv[j].z, zv.z, fmaf(wv[j].w, zv.w, qa[hh][j]))));
          ka[hh][j] = fmaf(kv[j].x, zv.x, fmaf(kv[j].y, zv.y,
                      fmaf(kv[j].z, zv.z, fmaf(kv[j].w, zv.w, ka[hh][j]))));
        }
      }
    }
  }

  float* Qs = lds;
  float* Ks = lds + 2048;
  float lse = 0.f;
#pragma unroll
  for (int hh = 0; hh < 4; ++hh) {
    __syncthreads();
#pragma unroll
    for (int j = 0; j < 8; ++j) {
      Qs[(w * 8 + j) * 64 + lane] = qa[hh][j];
      Ks[(w * 8 + j) * 64 + lane] = ka[hh][j];
    }
    __syncthreads();
    float av[16];
#pragma unroll
    for (int mm = 0; mm < 16; ++mm) av[mm] = 0.f;
    for (int rr = 0; rr < 32; ++rr) {
      float kv = Ks[rr * 64 + lane];
      const float* qrow = &Qs[rr * 64 + w * 16];
      float4 q0 = *(const float4*)(qrow + 0);
      float4 q1 = *(const float4*)(qrow + 4);
      float4 q2 = *(const float4*)(qrow + 8);
      float4 q3 = *(const float4*)(qrow + 12);
      av[0]  = fmaf(q0.x, kv, av[0]);  av[1]  = fmaf(q0.y, kv, av[1]);
      av[2]  = fmaf(q0.z, kv, av[2]);  av[3]  = fmaf(q0.w, kv, av[3]);
      av[4]  = fmaf(q1.x, kv, av[4]);  av[5]  = fmaf(q1.y, kv, av[5]);
      av[6]  = fmaf(q1.z, kv, av[6]);  av[7]  = fmaf(q1.w, kv, av[7]);
      av[8]  = fmaf(q2.x, kv, av[8]);  av[9]  = fmaf(q2.y, kv, av[9]);
      av[10] = fmaf(q2.z, kv, av[10]); av[11] = fmaf(q2.w, kv, av[11]);
      av[12] = fmaf(q3.x, kv, av[12]); av[13] = fmaf(q3.y, kv, av[13]);
      av[14] = fmaf(q3.z, kv, av[14]); av[15] = fmaf(q3.w, kv, av[15]);
    }
#pragma unroll
    for (int mm = 0; mm < 16; ++mm) {
      float e = __expf(GAMMA * av[mm]);
#pragma unroll
      for (int off = 32; off; off >>= 1) e += __shfl_xor(e, off, 64);
      lse += __logf(e);
    }
  }
  if (lane == 0) red[w] = lse;
  __syncthreads();
  if (t == 0)
    atomicAdd(out + b, -(red[0] + red[1] + red[2] + red[3]) * (1.0f / GAMMA));
}

// ---------------------------------------------------------------------------
extern "C" void kernel_launch(void* const* d_in, const int* in_sizes, int n_in,
                              void* d_out, int out_size, void* d_ws,
                              size_t ws_size, hipStream_t stream) {
  (void)in_sizes; (void)n_in; (void)out_size;
  const float* x  = (const float*)d_in[0];
  const float* z  = (const float*)d_in[1];
  const float* ew = (const float*)d_in[2];
  const float* eb = (const float*)d_in[3];
  const float* vb = (const float*)d_in[4];
  const float* pb = (const float*)d_in[5];
  const float* mw = (const float*)d_in[6];
  const float* wq = (const float*)d_in[7];
  const float* wk = (const float*)d_in[8];
  float* out = (float*)d_out;

  const size_t Z_B = (size_t)1024 * 64 * 256 * 2;   // 33.5 MB zb16
  const size_t MT_B = (size_t)1024 * 256 * 2;       // 0.5 MB mt16
  const size_t W_B = (size_t)8 * 32 * 256 * 2;      // 128 KB each wq16/wk16
  bool use_mfma = ws_size >= Z_B + MT_B + 2 * W_B;

  k_xz  <<<1024, 256, 0, stream>>>(x, z, vb, eb, pb, out);  // writes out[b]
  k_enc <<<1024, 256, 0, stream>>>(x, z, ew, out);          // atomic -=
  if (use_mfma) {
    ushort* zb16 = (ushort*)d_ws;
    ushort* mt16 = (ushort*)((char*)d_ws + Z_B);
    ushort* wq16 = (ushort*)((char*)d_ws + Z_B + MT_B);
    ushort* wk16 = (ushort*)((char*)d_ws + Z_B + MT_B + W_B);
    k_cvt    <<<16384, 256, 0, stream>>>((const float4*)z, (ushort4*)zb16);
    k_cvt    <<<64, 256, 0, stream>>>((const float4*)wq, (ushort4*)wq16);
    k_cvt    <<<64, 256, 0, stream>>>((const float4*)wk, (ushort4*)wk16);
    k_cvt_mw <<<128, 256, 0, stream>>>(mw, mt16);
    k_mem_mfma <<<4096, 256, 0, stream>>>(zb16, mt16, out); // atomic -=
    k_attn_mfma<<<1024, 256, 0, stream>>>(zb16, wq16, wk16, out); // atomic -=
  } else {
    k_mem <<<4096, 256, 0, stream>>>(z, mw, out);           // atomic -=
    k_attn<<<2048, 256, 0, stream>>>(z, wq, wk, out);       // atomic -=
  }
}

// Round 7
// 590.957 us; speedup vs baseline: 4.6744x; 1.2362x over previous
//
#include <hip/hip_runtime.h>
#include <hip/hip_bf16.h>

#define GAMMA 0.25f

// Shapes: B=1024, C=3, H=64, D=256, NP=64 (8x8 grid of 8x8 patches),
//         M=1024, NH=8, R=32, P=8.  fp32 in/out.  out[b] = quad - coupling.

typedef __attribute__((ext_vector_type(8))) short short8;  // 8 bf16 (4 VGPRs)
typedef __attribute__((ext_vector_type(4))) float f32x4;   // 4 fp32 acc

__device__ __forceinline__ float dot4(float4 a, float4 b) {
  return fmaf(a.x, b.x, fmaf(a.y, b.y, fmaf(a.z, b.z, a.w * b.w)));
}

__device__ __forceinline__ void fma4(float4& a, float s, float4 w) {
  a.x = fmaf(s, w.x, a.x); a.y = fmaf(s, w.y, a.y);
  a.z = fmaf(s, w.z, a.z); a.w = fmaf(s, w.w, a.w);
}

__device__ __forceinline__ ushort f2bf(float f) {
  __hip_bfloat16 h = __float2bfloat16(f);  // RNE
  return *reinterpret_cast<ushort*>(&h);
}

// 256-thread block sum; result valid on all threads.
__device__ __forceinline__ float block_sum_256(float v, float* tmp) {
#pragma unroll
  for (int off = 32; off; off >>= 1) v += __shfl_down(v, off, 64);
  int w = threadIdx.x >> 6;
  if ((threadIdx.x & 63) == 0) tmp[w] = v;
  __syncthreads();
  return tmp[0] + tmp[1] + tmp[2] + tmp[3];
}

// ---------------------------------------------------------------------------
// Kernel 1: quad_x + quad_z - phi_vis - phi_bias - phi_pos. Memory-bound.
// Sole non-atomic writer -> initializes out[b].
// ---------------------------------------------------------------------------
__global__ __launch_bounds__(256) void k_xz(const float* __restrict__ x,
                                            const float* __restrict__ z,
                                            const float* __restrict__ vb,
                                            const float* __restrict__ eb,
                                            const float* __restrict__ pb,
                                            float* __restrict__ out) {
  __shared__ float tmp[4];
  int b = blockIdx.x, t = threadIdx.x;
  const float4* xb = (const float4*)(x + (size_t)b * 12288);
  const float4* vb4 = (const float4*)vb;
  float s = 0.f;
  for (int i = t; i < 3072; i += 256) {
    float4 xv = xb[i];
    float4 bv = vb4[i];
    s += 0.5f * dot4(xv, xv) - dot4(bv, xv);
  }
  const float4* zb = (const float4*)(z + (size_t)b * 16384);
  const float4* pb4 = (const float4*)pb;
  const float4* eb4 = (const float4*)eb;
  for (int i = t; i < 4096; i += 256) {
    float4 zv = zb[i];
    float4 pv = pb4[i];
    float4 ev = eb4[i & 63];
    float4 c;
    c.x = pv.x + ev.x; c.y = pv.y + ev.y; c.z = pv.z + ev.z; c.w = pv.w + ev.w;
    s += 0.5f * dot4(zv, zv) - dot4(zv, c);
  }
  float r = block_sum_256(s, tmp);
  if (t == 0) out[b] = r;
}

// ---------------------------------------------------------------------------
// Kernel 2: phi_enc. One block per batch; x[b] staged in LDS (48 KB).
// ---------------------------------------------------------------------------
__global__ __launch_bounds__(256) void k_enc(const float* __restrict__ x,
                                             const float* __restrict__ z,
                                             const float* __restrict__ ew,
                                             float* __restrict__ out) {
  __shared__ float xs[12288];
  __shared__ float tmp[4];
  int b = blockIdx.x, t = threadIdx.x;
  const float4* xb4 = (const float4*)(x + (size_t)b * 12288);
  for (int i = t; i < 3072; i += 256) ((float4*)xs)[i] = xb4[i];
  __syncthreads();

  float acc[64];
#pragma unroll
  for (int p = 0; p < 64; ++p) acc[p] = 0.f;

  for (int k4 = 0; k4 < 48; ++k4) {
    float4 wv = *(const float4*)(ew + (size_t)t * 192 + k4 * 4);
    int c = k4 >> 4;
    int ii = (k4 >> 1) & 7;
    int jh = (k4 & 1) * 4;
    const float* base = xs + c * 4096 + ii * 64 + jh;
#pragma unroll
    for (int p = 0; p < 64; ++p) {
      float4 pv = *(const float4*)(base + (p >> 3) * 512 + (p & 7) * 8);
      acc[p] = fmaf(wv.x, pv.x,
               fmaf(wv.y, pv.y, fmaf(wv.z, pv.z, fmaf(wv.w, pv.w, acc[p]))));
    }
  }
  const float* zb = z + (size_t)b * 16384;
  float s = 0.f;
#pragma unroll
  for (int p = 0; p < 64; ++p) s += acc[p] * zb[p * 256 + t];
  float r = block_sum_256(s, tmp);
  if (t == 0) atomicAdd(out + b, -r);
}

// ---------------------------------------------------------------------------
// bf16 conversions (into d_ws).
// ---------------------------------------------------------------------------
__global__ __launch_bounds__(256) void k_cvt(const float4* __restrict__ z4,
                                             ushort4* __restrict__ o4) {
  int i = blockIdx.x * 256 + threadIdx.x;
  float4 v = z4[i];
  ushort4 o;
  o.x = f2bf(v.x); o.y = f2bf(v.y); o.z = f2bf(v.z); o.w = f2bf(v.w);
  o4[i] = o;
}

__global__ __launch_bounds__(256) void k_cvt_mw(const float* __restrict__ mw,
                                                ushort* __restrict__ mt) {
  int j = blockIdx.x * 256 + threadIdx.x;  // 128 blocks -> 32768 threads
  int m = j >> 5, k8 = j & 31;
  ushort tmp[8];
#pragma unroll
  for (int i = 0; i < 8; ++i) tmp[i] = f2bf(mw[(size_t)(k8 * 8 + i) * 1024 + m]);
  ushort4 a, c;
  a.x = tmp[0]; a.y = tmp[1]; a.z = tmp[2]; a.w = tmp[3];
  c.x = tmp[4]; c.y = tmp[5]; c.z = tmp[6]; c.w = tmp[7];
  *(ushort4*)(mt + (size_t)m * 256 + k8 * 8) = a;
  *(ushort4*)(mt + (size_t)m * 256 + k8 * 8 + 4) = c;
}

// ---------------------------------------------------------------------------
// Kernel 3 (MFMA v2): phi_mem = sum relu(z @ mw)^2.
// Block = (b, 256-m quarter ct); 4 waves; wave w owns p-rows 16w..+15 x all
// 256 m of the quarter (16 accs). ALL MFMA operands come from LDS:
//  - zf: z[b] A-frags staged ONCE in fragment order (32 KB; frag (w,ks,lane)
//    at idx*16B; lane-consecutive -> conflict-free b128).
//  - bf: mt quarter streamed in 8 K=32 chunks (16 KB) with 2-buffer pipeline:
//    prefetch chunk k+1 to regs -> compute chunk k (16 ds_read_b128 + 16
//    MFMA) -> ds_write prefetch -> barrier. L2 latency hides under compute.
// Fragment math identical to the R5-validated kernel (A/B same lane map;
// relu^2-sum is permutation-invariant) -> numerics unchanged.
// R6 counters showed the old version serialized ~128 L2 loads per wave
// (MfmaUtil 5.4%, VALUBusy 9.8%): per-iteration vmcnt stalls. This removes
// every global load from the MFMA path.
// ---------------------------------------------------------------------------
__global__ __launch_bounds__(256) void k_mem_mfma(const ushort* __restrict__ zb,
                                                  const ushort* __restrict__ mt,
                                                  float* __restrict__ out) {
  __shared__ ushort zf[2048 * 8];     // 32 KB: z[b] fragment-ordered
  __shared__ ushort bf[2][1024 * 8];  // 2 x 16 KB: mt chunk double-buffer
  __shared__ float tmp[4];
  const int t = threadIdx.x, l = t & 63, w = t >> 6;
  const int b = blockIdx.x >> 2, ct = blockIdx.x & 3;

  // Stage zf: frag i=(w2*8+ks)*64+l2 <- z[b][row=16w2+(l2&15)][ks*32+(l2>>4)*8]
#pragma unroll
  for (int j = 0; j < 8; ++j) {
    int i = t + j * 256;
    int l2 = i & 63, ks = (i >> 6) & 7, w2 = i >> 9;
    short8 v = *(const short8*)(zb + ((size_t)b * 64 + 16 * w2 + (l2 & 15)) * 256
                                + ks * 32 + (l2 >> 4) * 8);
    *(short8*)(zf + (size_t)i * 8) = v;
  }
  // Stage bf[0] = chunk 0: frag i=c*64+l2 <- mt[ct*256+16c+(l2&15)][(l2>>4)*8]
#pragma unroll
  for (int j = 0; j < 4; ++j) {
    int i = t + j * 256;
    int l2 = i & 63, c = i >> 6;
    short8 v = *(const short8*)(mt + ((size_t)ct * 256 + 16 * c + (l2 & 15)) * 256
                                + (l2 >> 4) * 8);
    *(short8*)(bf[0] + (size_t)i * 8) = v;
  }
  __syncthreads();

  f32x4 acc[16];
#pragma unroll
  for (int c = 0; c < 16; ++c) acc[c] = f32x4{0.f, 0.f, 0.f, 0.f};

  for (int kc = 0; kc < 8; ++kc) {
    int cur = kc & 1;
    short8 pre[4];
    if (kc < 7) {  // prefetch chunk kc+1 (in flight during compute below)
#pragma unroll
      for (int j = 0; j < 4; ++j) {
        int i = t + j * 256;
        int l2 = i & 63, c = i >> 6;
        pre[j] = *(const short8*)(mt + ((size_t)ct * 256 + 16 * c + (l2 & 15)) * 256
                                  + (kc + 1) * 32 + (l2 >> 4) * 8);
      }
    }
    short8 az = *(const short8*)(zf + (size_t)((w * 8 + kc) * 64 + l) * 8);
#pragma unroll
    for (int c = 0; c < 16; ++c) {
      short8 bv = *(const short8*)(bf[cur] + (size_t)(c * 64 + l) * 8);
      acc[c] = __builtin_amdgcn_mfma_f32_16x16x32_bf16(az, bv, acc[c], 0, 0, 0);
    }
    if (kc < 7) {
#pragma unroll
      for (int j = 0; j < 4; ++j)
        *(short8*)(bf[cur ^ 1] + (size_t)(t + j * 256) * 8) = pre[j];
    }
    __syncthreads();
  }

  float s = 0.f;
#pragma unroll
  for (int c = 0; c < 16; ++c) {
#pragma unroll
    for (int e = 0; e < 4; ++e) {
      float r = fmaxf(acc[c][e], 0.f);
      s = fmaf(r, r, s);
    }
  }
  float r = block_sum_256(s, tmp);
  if (t == 0) atomicAdd(out + b, -r);
}

// ---------------------------------------------------------------------------
// Kernel 4 (MFMA): phi_att. One block per b, 4 waves. (unchanged from R6)
// ---------------------------------------------------------------------------
__global__ __launch_bounds__(256) void k_attn_mfma(const ushort* __restrict__ zb,
                                                   const ushort* __restrict__ wq16,
                                                   const ushort* __restrict__ wk16,
                                                   float* __restrict__ out) {
  __shared__ ushort Qb[8 * 2560];  // [h][m][r], row stride 40 halfwords
  __shared__ ushort Kb[8 * 2560];  // [h][n][r]
  __shared__ float tmp[4];
  const int t = threadIdx.x, l = t & 63, w = t >> 6;
  const int b = blockIdx.x;
  const int q = l >> 4, m = l & 15;

  const ushort* Az = zb + ((size_t)b * 64 + 16 * w + m) * 256 + q * 8;
  short8 a[8];
#pragma unroll
  for (int ks = 0; ks < 8; ++ks) a[ks] = *(const short8*)(Az + ks * 32);

  for (int h = 0; h < 8; ++h) {
    f32x4 accq0 = f32x4{0.f, 0.f, 0.f, 0.f}, accq1 = accq0;
    f32x4 acck0 = accq0, acck1 = accq0;
    const ushort* Bq = wq16 + (size_t)h * 8192 + (size_t)m * 256 + q * 8;
    const ushort* Bk = wk16 + (size_t)h * 8192 + (size_t)m * 256 + q * 8;
#pragma unroll
    for (int ks = 0; ks < 8; ++ks) {
      short8 bq0 = *(const short8*)(Bq + ks * 32);
      short8 bq1 = *(const short8*)(Bq + 16 * 256 + ks * 32);
      short8 bk0 = *(const short8*)(Bk + ks * 32);
      short8 bk1 = *(const short8*)(Bk + 16 * 256 + ks * 32);
      accq0 = __builtin_amdgcn_mfma_f32_16x16x32_bf16(a[ks], bq0, accq0, 0, 0, 0);
      accq1 = __builtin_amdgcn_mfma_f32_16x16x32_bf16(a[ks], bq1, accq1, 0, 0, 0);
      acck0 = __builtin_amdgcn_mfma_f32_16x16x32_bf16(a[ks], bk0, acck0, 0, 0, 0);
      acck1 = __builtin_amdgcn_mfma_f32_16x16x32_bf16(a[ks], bk1, acck1, 0, 0, 0);
    }
    int rowbase = h * 2560 + (16 * w + 4 * q) * 40;
#pragma unroll
    for (int reg = 0; reg < 4; ++reg) {
      Qb[rowbase + reg * 40 + m]      = f2bf(accq0[reg]);
      Qb[rowbase + reg * 40 + 16 + m] = f2bf(accq1[reg]);
      Kb[rowbase + reg * 40 + m]      = f2bf(acck0[reg]);
      Kb[rowbase + reg * 40 + 16 + m] = f2bf(acck1[reg]);
    }
  }
  __syncthreads();

  float part = 0.f;
#pragma unroll
  for (int h = 0; h < 8; ++h) {
    short8 qa = *(const short8*)&Qb[h * 2560 + (16 * w + m) * 40 + q * 8];
    f32x4 acc[4];
#pragma unroll
    for (int nt = 0; nt < 4; ++nt) {
      short8 kb = *(const short8*)&Kb[h * 2560 + (16 * nt + m) * 40 + q * 8];
      acc[nt] = __builtin_amdgcn_mfma_f32_16x16x32_bf16(
          qa, kb, f32x4{0.f, 0.f, 0.f, 0.f}, 0, 0, 0);
    }
#pragma unroll
    for (int reg = 0; reg < 4; ++reg) {
      float e = __expf(GAMMA * acc[0][reg]) + __expf(GAMMA * acc[1][reg]) +
                __expf(GAMMA * acc[2][reg]) + __expf(GAMMA * acc[3][reg]);
      e += __shfl_xor(e, 1, 64);
      e += __shfl_xor(e, 2, 64);
      e += __shfl_xor(e, 4, 64);
      e += __shfl_xor(e, 8, 64);
      part += (m == 0) ? __logf(e) : 0.f;
    }
  }
  float tot = block_sum_256(part, tmp);
  if (t == 0) atomicAdd(out + b, -tot * (1.0f / GAMMA));
}

// ---------------------------------------------------------------------------
// fp32 fallbacks (used only if ws_size too small).
// ---------------------------------------------------------------------------
__global__ __launch_bounds__(256) void k_mem(const float* __restrict__ z,
                                             const float* __restrict__ mw,
                                             float* __restrict__ out) {
  __shared__ float zs[16 * 256];
  __shared__ float tmp[4];
  int b = blockIdx.x >> 2, pt = blockIdx.x & 3, t = threadIdx.x;
  const float4* zb4 = (const float4*)(z + (size_t)b * 16384 + pt * 4096);
  for (int i = t; i < 1024; i += 256) ((float4*)zs)[i] = zb4[i];
  __syncthreads();

  const float4* m4 = (const float4*)mw;
  float4 acc[16];
#pragma unroll
  for (int pp = 0; pp < 16; ++pp) acc[pp] = make_float4(0.f, 0.f, 0.f, 0.f);

#pragma unroll 2
  for (int k4 = 0; k4 < 64; ++k4) {
    float4 w0 = m4[(4 * k4 + 0) * 256 + t];
    float4 w1 = m4[(4 * k4 + 1) * 256 + t];
    float4 w2 = m4[(4 * k4 + 2) * 256 + t];
    float4 w3 = m4[(4 * k4 + 3) * 256 + t];
#pragma unroll
    for (int pp = 0; pp < 16; ++pp) {
      float4 zv = *(const float4*)&zs[pp * 256 + k4 * 4];
      fma4(acc[pp], zv.x, w0);
      fma4(acc[pp], zv.y, w1);
      fma4(acc[pp], zv.z, w2);
      fma4(acc[pp], zv.w, w3);
    }
  }
  float total = 0.f;
#pragma unroll
  for (int pp = 0; pp < 16; ++pp) {
    float r;
    r = fmaxf(acc[pp].x, 0.f); total = fmaf(r, r, total);
    r = fmaxf(acc[pp].y, 0.f); total = fmaf(r, r, total);
    r = fmaxf(acc[pp].z, 0.f); total = fmaf(r, r, total);
    r = fmaxf(acc[pp].w, 0.f); total = fmaf(r, r, total);
  }
  float r = block_sum_256(total, tmp);
  if (t == 0) atomicAdd(out + b, -r);
}

__global__ __launch_bounds__(256) void k_attn(const float* __restrict__ z,
                                              const float* __restrict__ wq,
                                              const float* __restrict__ wk,
                                              float* __restrict__ out) {
  __shared__ float lds[8192];
  __shared__ float red[4];
  const int b = blockIdx.x >> 1, half = blockIdx.x & 1;
  const int t = threadIdx.x;
  const int lane = t & 63;
  const int w = __builtin_amdgcn_readfirstlane(t >> 6);
  const float4* zb4 = (const float4*)(z + (size_t)b * 16384);

  float qa[4][8], ka[4][8];
#pragma unroll
  for (int hh = 0; hh < 4; ++hh)
#pragma unroll
    for (int j = 0; j < 8; ++j) { qa[hh][j] = 0.f; ka[hh][j] = 0.f; }

  float4* lds4 = (float4*)lds;
  for (int dc = 0; dc < 2; ++dc) {
    __syncthreads();
    for (int i = t; i < 2048; i += 256) {
      int p = i >> 5, ld4 = i & 31;
      lds4[ld4 * 64 + (p ^ (ld4 & 7))] = zb4[p * 64 + dc * 32 + ld4];
    }
    __syncthreads();
#pragma unroll
    for (int hh = 0; hh < 4; ++hh) {
      int h = half * 4 + hh;
      const float* Wqb = wq + (size_t)h * 8192 + (size_t)(w * 8) * 256 + dc * 128;
      const float* Wkb = wk + (size_t)h * 8192 + (size_t)(w * 8) * 256 + dc * 128;
      for (int ld4 = 0; ld4 < 32; ++ld4) {
        float4 wv[8], kv[8];
#pragma unroll
        for (int j = 0; j < 8; ++j) {
          wv[j] = *(const float4*)(Wqb + j * 256 + ld4 * 4);
          kv[j] = *(const float4*)(Wkb + j * 256 + ld4 * 4);
        }
        float4 zv = lds4[ld4 * 64 + (lane ^ (ld4 & 7))];
#pragma unroll
        for (int j = 0; j < 8; ++j) {
          qa[hh][j] = fmaf(wv[j].x, zv.x, fmaf(wv[j].y, zv.y,
                      fmaf(wv[j].z, zv.z, fmaf(wv[j].w, zv.w, qa[hh][j]))));
          ka[hh][j] = fmaf(kv[j].x, zv.x, fmaf(kv[j].y, zv.y,
                      fmaf(kv[j].z, zv.z, fmaf(kv[j].w, zv.w, ka[hh][j]))));
        }
      }
    }
  }

  float* Qs = lds;
  float* Ks = lds + 2048;
  float lse = 0.f;
#pragma unroll
  for (int hh = 0; hh < 4; ++hh) {
    __syncthreads();
#pragma unroll
    for (int j = 0; j < 8; ++j) {
      Qs[(w * 8 + j) * 64 + lane] = qa[hh][j];
      Ks[(w * 8 + j) * 64 + lane] = ka[hh][j];
    }
    __syncthreads();
    float av[16];
#pragma unroll
    for (int mm = 0; mm < 16; ++mm) av[mm] = 0.f;
    for (int rr = 0; rr < 32; ++rr) {
      float kv = Ks[rr * 64 + lane];
      const float* qrow = &Qs[rr * 64 + w * 16];
      float4 q0 = *(const float4*)(qrow + 0);
      float4 q1 = *(const float4*)(qrow + 4);
      float4 q2 = *(const float4*)(qrow + 8);
      float4 q3 = *(const float4*)(qrow + 12);
      av[0]  = fmaf(q0.x, kv, av[0]);  av[1]  = fmaf(q0.y, kv, av[1]);
      av[2]  = fmaf(q0.z, kv, av[2]);  av[3]  = fmaf(q0.w, kv, av[3]);
      av[4]  = fmaf(q1.x, kv, av[4]);  av[5]  = fmaf(q1.y, kv, av[5]);
      av[6]  = fmaf(q1.z, kv, av[6]);  av[7]  = fmaf(q1.w, kv, av[7]);
      av[8]  = fmaf(q2.x, kv, av[8]);  av[9]  = fmaf(q2.y, kv, av[9]);
      av[10] = fmaf(q2.z, kv, av[10]); av[11] = fmaf(q2.w, kv, av[11]);
      av[12] = fmaf(q3.x, kv, av[12]); av[13] = fmaf(q3.y, kv, av[13]);
      av[14] = fmaf(q3.z, kv, av[14]); av[15] = fmaf(q3.w, kv, av[15]);
    }
#pragma unroll
    for (int mm = 0; mm < 16; ++mm) {
      float e = __expf(GAMMA * av[mm]);
#pragma unroll
      for (int off = 32; off; off >>= 1) e += __shfl_xor(e, off, 64);
      lse += __logf(e);
    }
  }
  if (lane == 0) red[w] = lse;
  __syncthreads();
  if (t == 0)
    atomicAdd(out + b, -(red[0] + red[1] + red[2] + red[3]) * (1.0f / GAMMA));
}

// ---------------------------------------------------------------------------
extern "C" void kernel_launch(void* const* d_in, const int* in_sizes, int n_in,
                              void* d_out, int out_size, void* d_ws,
                              size_t ws_size, hipStream_t stream) {
  (void)in_sizes; (void)n_in; (void)out_size;
  const float* x  = (const float*)d_in[0];
  const float* z  = (const float*)d_in[1];
  const float* ew = (const float*)d_in[2];
  const float* eb = (const float*)d_in[3];
  const float* vb = (const float*)d_in[4];
  const float* pb = (const float*)d_in[5];
  const float* mw = (const float*)d_in[6];
  const float* wq = (const float*)d_in[7];
  const float* wk = (const float*)d_in[8];
  float* out = (float*)d_out;

  const size_t Z_B = (size_t)1024 * 64 * 256 * 2;   // 33.5 MB zb16
  const size_t MT_B = (size_t)1024 * 256 * 2;       // 0.5 MB mt16
  const size_t W_B = (size_t)8 * 32 * 256 * 2;      // 128 KB each wq16/wk16
  bool use_mfma = ws_size >= Z_B + MT_B + 2 * W_B;

  k_xz  <<<1024, 256, 0, stream>>>(x, z, vb, eb, pb, out);  // writes out[b]
  k_enc <<<1024, 256, 0, stream>>>(x, z, ew, out);          // atomic -=
  if (use_mfma) {
    ushort* zb16 = (ushort*)d_ws;
    ushort* mt16 = (ushort*)((char*)d_ws + Z_B);
    ushort* wq16 = (ushort*)((char*)d_ws + Z_B + MT_B);
    ushort* wk16 = (ushort*)((char*)d_ws + Z_B + MT_B + W_B);
    k_cvt    <<<16384, 256, 0, stream>>>((const float4*)z, (ushort4*)zb16);
    k_cvt    <<<64, 256, 0, stream>>>((const float4*)wq, (ushort4*)wq16);
    k_cvt    <<<64, 256, 0, stream>>>((const float4*)wk, (ushort4*)wk16);
    k_cvt_mw <<<128, 256, 0, stream>>>(mw, mt16);
    k_mem_mfma <<<4096, 256, 0, stream>>>(zb16, mt16, out); // atomic -=
    k_attn_mfma<<<1024, 256, 0, stream>>>(zb16, wq16, wk16, out); // atomic -=
  } else {
    k_mem <<<4096, 256, 0, stream>>>(z, mw, out);           // atomic -=
    k_attn<<<2048, 256, 0, stream>>>(z, wq, wk, out);       // atomic -=
  }
}

// Round 8
// 435.300 us; speedup vs baseline: 6.3459x; 1.3576x over previous
//
#include <hip/hip_runtime.h>
#include <hip/hip_bf16.h>

#define GAMMA 0.25f

// Shapes: B=1024, C=3, H=64, D=256, NP=64 (8x8 grid of 8x8 patches),
//         M=1024, NH=8, R=32, P=8.  fp32 in/out.  out[b] = quad - coupling.

typedef __attribute__((ext_vector_type(8))) short short8;  // 8 bf16 (4 VGPRs)
typedef __attribute__((ext_vector_type(4))) float f32x4;   // 4 fp32 acc

__device__ __forceinline__ float dot4(float4 a, float4 b) {
  return fmaf(a.x, b.x, fmaf(a.y, b.y, fmaf(a.z, b.z, a.w * b.w)));
}

__device__ __forceinline__ void fma4(float4& a, float s, float4 w) {
  a.x = fmaf(s, w.x, a.x); a.y = fmaf(s, w.y, a.y);
  a.z = fmaf(s, w.z, a.z); a.w = fmaf(s, w.w, a.w);
}

__device__ __forceinline__ ushort f2bf(float f) {
  __hip_bfloat16 h = __float2bfloat16(f);  // RNE
  return *reinterpret_cast<ushort*>(&h);
}

// 256-thread block sum; result valid on all threads.
__device__ __forceinline__ float block_sum_256(float v, float* tmp) {
#pragma unroll
  for (int off = 32; off; off >>= 1) v += __shfl_down(v, off, 64);
  int w = threadIdx.x >> 6;
  if ((threadIdx.x & 63) == 0) tmp[w] = v;
  __syncthreads();
  return tmp[0] + tmp[1] + tmp[2] + tmp[3];
}

// ---------------------------------------------------------------------------
// Kernel 1 (fused): quad/vis/bias/pos terms AND x,z -> bf16 conversion.
// k_xz already streams all of x and z; writing x16/zb16 here kills the
// separate z-cvt kernel and a second 50 MB x read. Sole non-atomic writer.
// ---------------------------------------------------------------------------
__global__ __launch_bounds__(256) void k_xz_cvt(const float* __restrict__ x,
                                                const float* __restrict__ z,
                                                const float* __restrict__ vb,
                                                const float* __restrict__ eb,
                                                const float* __restrict__ pb,
                                                float* __restrict__ out,
                                                ushort* __restrict__ x16,
                                                ushort* __restrict__ zb16) {
  __shared__ float tmp[4];
  int b = blockIdx.x, t = threadIdx.x;
  const float4* xb = (const float4*)(x + (size_t)b * 12288);
  const float4* vb4 = (const float4*)vb;
  ushort4* x16o = (ushort4*)(x16 + (size_t)b * 12288);
  float s = 0.f;
  for (int i = t; i < 3072; i += 256) {
    float4 xv = xb[i];
    float4 bv = vb4[i];
    s += 0.5f * dot4(xv, xv) - dot4(bv, xv);
    ushort4 o;
    o.x = f2bf(xv.x); o.y = f2bf(xv.y); o.z = f2bf(xv.z); o.w = f2bf(xv.w);
    x16o[i] = o;
  }
  const float4* zb = (const float4*)(z + (size_t)b * 16384);
  const float4* pb4 = (const float4*)pb;
  const float4* eb4 = (const float4*)eb;
  ushort4* z16o = (ushort4*)(zb16 + (size_t)b * 16384);
  for (int i = t; i < 4096; i += 256) {
    float4 zv = zb[i];
    float4 pv = pb4[i];
    float4 ev = eb4[i & 63];
    float4 c;
    c.x = pv.x + ev.x; c.y = pv.y + ev.y; c.z = pv.z + ev.z; c.w = pv.w + ev.w;
    s += 0.5f * dot4(zv, zv) - dot4(zv, c);
    ushort4 o;
    o.x = f2bf(zv.x); o.y = f2bf(zv.y); o.z = f2bf(zv.z); o.w = f2bf(zv.w);
    z16o[i] = o;
  }
  float r = block_sum_256(s, tmp);
  if (t == 0) out[b] = r;
}

// ---------------------------------------------------------------------------
// All small weight conversions in ONE launch (block ranges):
// [0,64) wq plain, [64,128) wk plain, [128,176) ew plain, [176,304) mw-transp.
// ---------------------------------------------------------------------------
__global__ __launch_bounds__(256) void k_cvt_weights(
    const float4* __restrict__ wq4, const float4* __restrict__ wk4,
    const float4* __restrict__ ew4, const float* __restrict__ mw,
    ushort4* __restrict__ wq16, ushort4* __restrict__ wk16,
    ushort4* __restrict__ ew16, ushort* __restrict__ mt) {
  int bid = blockIdx.x, t = threadIdx.x;
  if (bid < 176) {
    const float4* src; ushort4* dst; int i;
    if (bid < 64)       { src = wq4; dst = wq16; i = bid * 256 + t; }
    else if (bid < 128) { src = wk4; dst = wk16; i = (bid - 64) * 256 + t; }
    else                { src = ew4; dst = ew16; i = (bid - 128) * 256 + t; }
    float4 v = src[i];
    ushort4 o;
    o.x = f2bf(v.x); o.y = f2bf(v.y); o.z = f2bf(v.z); o.w = f2bf(v.w);
    dst[i] = o;
  } else {
    int j = (bid - 176) * 256 + t;  // 32768 threads
    int m = j >> 5, k8 = j & 31;
    ushort tmp[8];
#pragma unroll
    for (int i = 0; i < 8; ++i)
      tmp[i] = f2bf(mw[(size_t)(k8 * 8 + i) * 1024 + m]);
    ushort4 a, c;
    a.x = tmp[0]; a.y = tmp[1]; a.z = tmp[2]; a.w = tmp[3];
    c.x = tmp[4]; c.y = tmp[5]; c.z = tmp[6]; c.w = tmp[7];
    *(ushort4*)(mt + (size_t)m * 256 + k8 * 8) = a;
    *(ushort4*)(mt + (size_t)m * 256 + k8 * 8 + 4) = c;
  }
}

// ---------------------------------------------------------------------------
// Kernel 2 (MFMA): phi_enc = sum_{p,d} (Xp @ W^T)[p,d] * z[b,p,d].
// Per-b GEMM M=64(patch) N=256(d) K=192(c*64+i*8+j), same validated structure
// as k_mem_mfma v2: A-frags (x16) in regs, B (ew16, 96 KB L2-hot) streamed in
// 6 K=32 chunks through a 16 KB LDS double-buffer w/ reg prefetch.
// Epilogue: dot acc against fp32 z via C-layout (p=16w+4q+reg, d=16ct+m).
// R7 counters: old k_enc was LDS-broadcast-bound (3072 ds_read_b128/thread,
// 200 us vs 41 us FMA floor).
// ---------------------------------------------------------------------------
__global__ __launch_bounds__(256) void k_enc_mfma(const ushort* __restrict__ x16,
                                                  const ushort* __restrict__ ew16,
                                                  const float* __restrict__ z,
                                                  float* __restrict__ out) {
  __shared__ ushort bfr[2][1024 * 8];  // 2 x 16 KB
  __shared__ float tmp[4];
  const int t = threadIdx.x, l = t & 63, w = t >> 6;
  const int q = l >> 4, m = l & 15;
  const int b = blockIdx.x;

  // A-frags: patch p=16w+m, k = ks*32 + q*8 (+0..7 contiguous j).
  const int p = 16 * w + m, gi = p >> 3, gj = p & 7;
  short8 a[6];
#pragma unroll
  for (int ks = 0; ks < 6; ++ks) {
    int k0 = ks * 32 + q * 8;
    int c = k0 >> 6, ii = (k0 & 63) >> 3;
    a[ks] = *(const short8*)(x16 + (size_t)b * 12288 + c * 4096 +
                             (gi * 8 + ii) * 64 + gj * 8);
  }
  // Stage B chunk 0: frag i2 = ct*64+l2 <- ew16[d=16ct+(l2&15)][(l2>>4)*8]
#pragma unroll
  for (int j = 0; j < 4; ++j) {
    int i2 = t + j * 256, l2 = i2 & 63, ct = i2 >> 6;
    short8 v = *(const short8*)(ew16 + (size_t)(16 * ct + (l2 & 15)) * 192 +
                                (l2 >> 4) * 8);
    *(short8*)(bfr[0] + (size_t)i2 * 8) = v;
  }
  __syncthreads();

  f32x4 acc[16];
#pragma unroll
  for (int c = 0; c < 16; ++c) acc[c] = f32x4{0.f, 0.f, 0.f, 0.f};

  for (int ks = 0; ks < 6; ++ks) {
    int cur = ks & 1;
    short8 pre[4];
    if (ks < 5) {
#pragma unroll
      for (int j = 0; j < 4; ++j) {
        int i2 = t + j * 256, l2 = i2 & 63, ct = i2 >> 6;
        pre[j] = *(const short8*)(ew16 + (size_t)(16 * ct + (l2 & 15)) * 192 +
                                  (ks + 1) * 32 + (l2 >> 4) * 8);
      }
    }
#pragma unroll
    for (int ct = 0; ct < 16; ++ct) {
      short8 bv = *(const short8*)(bfr[cur] + (size_t)(ct * 64 + l) * 8);
      acc[ct] = __builtin_amdgcn_mfma_f32_16x16x32_bf16(a[ks], bv, acc[ct], 0, 0, 0);
    }
    if (ks < 5) {
#pragma unroll
      for (int j = 0; j < 4; ++j)
        *(short8*)(bfr[cur ^ 1] + (size_t)(t + j * 256) * 8) = pre[j];
    }
    __syncthreads();
  }

  const float* zb = z + (size_t)b * 16384;
  float s = 0.f;
#pragma unroll
  for (int ct = 0; ct < 16; ++ct) {
#pragma unroll
    for (int reg = 0; reg < 4; ++reg) {
      int pp = 16 * w + 4 * q + reg;
      s = fmaf(acc[ct][reg], zb[pp * 256 + 16 * ct + m], s);
    }
  }
  float r = block_sum_256(s, tmp);
  if (t == 0) atomicAdd(out + b, -r);
}

// ---------------------------------------------------------------------------
// Kernel 3 (MFMA v2): phi_mem = sum relu(z @ mw)^2. (unchanged from R7)
// ---------------------------------------------------------------------------
__global__ __launch_bounds__(256) void k_mem_mfma(const ushort* __restrict__ zb,
                                                  const ushort* __restrict__ mt,
                                                  float* __restrict__ out) {
  __shared__ ushort zf[2048 * 8];     // 32 KB: z[b] fragment-ordered
  __shared__ ushort bf[2][1024 * 8];  // 2 x 16 KB: mt chunk double-buffer
  __shared__ float tmp[4];
  const int t = threadIdx.x, l = t & 63, w = t >> 6;
  const int b = blockIdx.x >> 2, ct = blockIdx.x & 3;

#pragma unroll
  for (int j = 0; j < 8; ++j) {
    int i = t + j * 256;
    int l2 = i & 63, ks = (i >> 6) & 7, w2 = i >> 9;
    short8 v = *(const short8*)(zb + ((size_t)b * 64 + 16 * w2 + (l2 & 15)) * 256
                                + ks * 32 + (l2 >> 4) * 8);
    *(short8*)(zf + (size_t)i * 8) = v;
  }
#pragma unroll
  for (int j = 0; j < 4; ++j) {
    int i = t + j * 256;
    int l2 = i & 63, c = i >> 6;
    short8 v = *(const short8*)(mt + ((size_t)ct * 256 + 16 * c + (l2 & 15)) * 256
                                + (l2 >> 4) * 8);
    *(short8*)(bf[0] + (size_t)i * 8) = v;
  }
  __syncthreads();

  f32x4 acc[16];
#pragma unroll
  for (int c = 0; c < 16; ++c) acc[c] = f32x4{0.f, 0.f, 0.f, 0.f};

  for (int kc = 0; kc < 8; ++kc) {
    int cur = kc & 1;
    short8 pre[4];
    if (kc < 7) {
#pragma unroll
      for (int j = 0; j < 4; ++j) {
        int i = t + j * 256;
        int l2 = i & 63, c = i >> 6;
        pre[j] = *(const short8*)(mt + ((size_t)ct * 256 + 16 * c + (l2 & 15)) * 256
                                  + (kc + 1) * 32 + (l2 >> 4) * 8);
      }
    }
    short8 az = *(const short8*)(zf + (size_t)((w * 8 + kc) * 64 + l) * 8);
#pragma unroll
    for (int c = 0; c < 16; ++c) {
      short8 bv = *(const short8*)(bf[cur] + (size_t)(c * 64 + l) * 8);
      acc[c] = __builtin_amdgcn_mfma_f32_16x16x32_bf16(az, bv, acc[c], 0, 0, 0);
    }
    if (kc < 7) {
#pragma unroll
      for (int j = 0; j < 4; ++j)
        *(short8*)(bf[cur ^ 1] + (size_t)(t + j * 256) * 8) = pre[j];
    }
    __syncthreads();
  }

  float s = 0.f;
#pragma unroll
  for (int c = 0; c < 16; ++c) {
#pragma unroll
    for (int e = 0; e < 4; ++e) {
      float r = fmaxf(acc[c][e], 0.f);
      s = fmaf(r, r, s);
    }
  }
  float r = block_sum_256(s, tmp);
  if (t == 0) atomicAdd(out + b, -r);
}

// ---------------------------------------------------------------------------
// Kernel 4 (MFMA): phi_att. One block per b, 4 waves. (unchanged from R7)
// ---------------------------------------------------------------------------
__global__ __launch_bounds__(256) void k_attn_mfma(const ushort* __restrict__ zb,
                                                   const ushort* __restrict__ wq16,
                                                   const ushort* __restrict__ wk16,
                                                   float* __restrict__ out) {
  __shared__ ushort Qb[8 * 2560];  // [h][m][r], row stride 40 halfwords
  __shared__ ushort Kb[8 * 2560];  // [h][n][r]
  __shared__ float tmp[4];
  const int t = threadIdx.x, l = t & 63, w = t >> 6;
  const int b = blockIdx.x;
  const int q = l >> 4, m = l & 15;

  const ushort* Az = zb + ((size_t)b * 64 + 16 * w + m) * 256 + q * 8;
  short8 a[8];
#pragma unroll
  for (int ks = 0; ks < 8; ++ks) a[ks] = *(const short8*)(Az + ks * 32);

  for (int h = 0; h < 8; ++h) {
    f32x4 accq0 = f32x4{0.f, 0.f, 0.f, 0.f}, accq1 = accq0;
    f32x4 acck0 = accq0, acck1 = accq0;
    const ushort* Bq = wq16 + (size_t)h * 8192 + (size_t)m * 256 + q * 8;
    const ushort* Bk = wk16 + (size_t)h * 8192 + (size_t)m * 256 + q * 8;
#pragma unroll
    for (int ks = 0; ks < 8; ++ks) {
      short8 bq0 = *(const short8*)(Bq + ks * 32);
      short8 bq1 = *(const short8*)(Bq + 16 * 256 + ks * 32);
      short8 bk0 = *(const short8*)(Bk + ks * 32);
      short8 bk1 = *(const short8*)(Bk + 16 * 256 + ks * 32);
      accq0 = __builtin_amdgcn_mfma_f32_16x16x32_bf16(a[ks], bq0, accq0, 0, 0, 0);
      accq1 = __builtin_amdgcn_mfma_f32_16x16x32_bf16(a[ks], bq1, accq1, 0, 0, 0);
      acck0 = __builtin_amdgcn_mfma_f32_16x16x32_bf16(a[ks], bk0, acck0, 0, 0, 0);
      acck1 = __builtin_amdgcn_mfma_f32_16x16x32_bf16(a[ks], bk1, acck1, 0, 0, 0);
    }
    int rowbase = h * 2560 + (16 * w + 4 * q) * 40;
#pragma unroll
    for (int reg = 0; reg < 4; ++reg) {
      Qb[rowbase + reg * 40 + m]      = f2bf(accq0[reg]);
      Qb[rowbase + reg * 40 + 16 + m] = f2bf(accq1[reg]);
      Kb[rowbase + reg * 40 + m]      = f2bf(acck0[reg]);
      Kb[rowbase + reg * 40 + 16 + m] = f2bf(acck1[reg]);
    }
  }
  __syncthreads();

  float part = 0.f;
#pragma unroll
  for (int h = 0; h < 8; ++h) {
    short8 qa = *(const short8*)&Qb[h * 2560 + (16 * w + m) * 40 + q * 8];
    f32x4 acc[4];
#pragma unroll
    for (int nt = 0; nt < 4; ++nt) {
      short8 kb = *(const short8*)&Kb[h * 2560 + (16 * nt + m) * 40 + q * 8];
      acc[nt] = __builtin_amdgcn_mfma_f32_16x16x32_bf16(
          qa, kb, f32x4{0.f, 0.f, 0.f, 0.f}, 0, 0, 0);
    }
#pragma unroll
    for (int reg = 0; reg < 4; ++reg) {
      float e = __expf(GAMMA * acc[0][reg]) + __expf(GAMMA * acc[1][reg]) +
                __expf(GAMMA * acc[2][reg]) + __expf(GAMMA * acc[3][reg]);
      e += __shfl_xor(e, 1, 64);
      e += __shfl_xor(e, 2, 64);
      e += __shfl_xor(e, 4, 64);
      e += __shfl_xor(e, 8, 64);
      part += (m == 0) ? __logf(e) : 0.f;
    }
  }
  float tot = block_sum_256(part, tmp);
  if (t == 0) atomicAdd(out + b, -tot * (1.0f / GAMMA));
}

// ---------------------------------------------------------------------------
// Fallback kernels (mid/low ws tiers).
// ---------------------------------------------------------------------------
__global__ __launch_bounds__(256) void k_xz(const float* __restrict__ x,
                                            const float* __restrict__ z,
                                            const float* __restrict__ vb,
                                            const float* __restrict__ eb,
                                            const float* __restrict__ pb,
                                            float* __restrict__ out) {
  __shared__ float tmp[4];
  int b = blockIdx.x, t = threadIdx.x;
  const float4* xb = (const float4*)(x + (size_t)b * 12288);
  const float4* vb4 = (const float4*)vb;
  float s = 0.f;
  for (int i = t; i < 3072; i += 256) {
    float4 xv = xb[i];
    float4 bv = vb4[i];
    s += 0.5f * dot4(xv, xv) - dot4(bv, xv);
  }
  const float4* zb = (const float4*)(z + (size_t)b * 16384);
  const float4* pb4 = (const float4*)pb;
  const float4* eb4 = (const float4*)eb;
  for (int i = t; i < 4096; i += 256) {
    float4 zv = zb[i];
    float4 pv = pb4[i];
    float4 ev = eb4[i & 63];
    float4 c;
    c.x = pv.x + ev.x; c.y = pv.y + ev.y; c.z = pv.z + ev.z; c.w = pv.w + ev.w;
    s += 0.5f * dot4(zv, zv) - dot4(zv, c);
  }
  float r = block_sum_256(s, tmp);
  if (t == 0) out[b] = r;
}

__global__ __launch_bounds__(256) void k_enc(const float* __restrict__ x,
                                             const float* __restrict__ z,
                                             const float* __restrict__ ew,
                                             float* __restrict__ out) {
  __shared__ float xs[12288];
  __shared__ float tmp[4];
  int b = blockIdx.x, t = threadIdx.x;
  const float4* xb4 = (const float4*)(x + (size_t)b * 12288);
  for (int i = t; i < 3072; i += 256) ((float4*)xs)[i] = xb4[i];
  __syncthreads();

  float acc[64];
#pragma unroll
  for (int p = 0; p < 64; ++p) acc[p] = 0.f;

  for (int k4 = 0; k4 < 48; ++k4) {
    float4 wv = *(const float4*)(ew + (size_t)t * 192 + k4 * 4);
    int c = k4 >> 4;
    int ii = (k4 >> 1) & 7;
    int jh = (k4 & 1) * 4;
    const float* base = xs + c * 4096 + ii * 64 + jh;
#pragma unroll
    for (int p = 0; p < 64; ++p) {
      float4 pv = *(const float4*)(base + (p >> 3) * 512 + (p & 7) * 8);
      acc[p] = fmaf(wv.x, pv.x,
               fmaf(wv.y, pv.y, fmaf(wv.z, pv.z, fmaf(wv.w, pv.w, acc[p]))));
    }
  }
  const float* zb = z + (size_t)b * 16384;
  float s = 0.f;
#pragma unroll
  for (int p = 0; p < 64; ++p) s += acc[p] * zb[p * 256 + t];
  float r = block_sum_256(s, tmp);
  if (t == 0) atomicAdd(out + b, -r);
}

__global__ __launch_bounds__(256) void k_cvt(const float4* __restrict__ z4,
                                             ushort4* __restrict__ o4) {
  int i = blockIdx.x * 256 + threadIdx.x;
  float4 v = z4[i];
  ushort4 o;
  o.x = f2bf(v.x); o.y = f2bf(v.y); o.z = f2bf(v.z); o.w = f2bf(v.w);
  o4[i] = o;
}

__global__ __launch_bounds__(256) void k_cvt_mw(const float* __restrict__ mw,
                                                ushort* __restrict__ mt) {
  int j = blockIdx.x * 256 + threadIdx.x;
  int m = j >> 5, k8 = j & 31;
  ushort tmp[8];
#pragma unroll
  for (int i = 0; i < 8; ++i) tmp[i] = f2bf(mw[(size_t)(k8 * 8 + i) * 1024 + m]);
  ushort4 a, c;
  a.x = tmp[0]; a.y = tmp[1]; a.z = tmp[2]; a.w = tmp[3];
  c.x = tmp[4]; c.y = tmp[5]; c.z = tmp[6]; c.w = tmp[7];
  *(ushort4*)(mt + (size_t)m * 256 + k8 * 8) = a;
  *(ushort4*)(mt + (size_t)m * 256 + k8 * 8 + 4) = c;
}

__global__ __launch_bounds__(256) void k_mem(const float* __restrict__ z,
                                             const float* __restrict__ mw,
                                             float* __restrict__ out) {
  __shared__ float zs[16 * 256];
  __shared__ float tmp[4];
  int b = blockIdx.x >> 2, pt = blockIdx.x & 3, t = threadIdx.x;
  const float4* zb4 = (const float4*)(z + (size_t)b * 16384 + pt * 4096);
  for (int i = t; i < 1024; i += 256) ((float4*)zs)[i] = zb4[i];
  __syncthreads();

  const float4* m4 = (const float4*)mw;
  float4 acc[16];
#pragma unroll
  for (int pp = 0; pp < 16; ++pp) acc[pp] = make_float4(0.f, 0.f, 0.f, 0.f);

#pragma unroll 2
  for (int k4 = 0; k4 < 64; ++k4) {
    float4 w0 = m4[(4 * k4 + 0) * 256 + t];
    float4 w1 = m4[(4 * k4 + 1) * 256 + t];
    float4 w2 = m4[(4 * k4 + 2) * 256 + t];
    float4 w3 = m4[(4 * k4 + 3) * 256 + t];
#pragma unroll
    for (int pp = 0; pp < 16; ++pp) {
      float4 zv = *(const float4*)&zs[pp * 256 + k4 * 4];
      fma4(acc[pp], zv.x, w0);
      fma4(acc[pp], zv.y, w1);
      fma4(acc[pp], zv.z, w2);
      fma4(acc[pp], zv.w, w3);
    }
  }
  float total = 0.f;
#pragma unroll
  for (int pp = 0; pp < 16; ++pp) {
    float r;
    r = fmaxf(acc[pp].x, 0.f); total = fmaf(r, r, total);
    r = fmaxf(acc[pp].y, 0.f); total = fmaf(r, r, total);
    r = fmaxf(acc[pp].z, 0.f); total = fmaf(r, r, total);
    r = fmaxf(acc[pp].w, 0.f); total = fmaf(r, r, total);
  }
  float r = block_sum_256(total, tmp);
  if (t == 0) atomicAdd(out + b, -r);
}

__global__ __launch_bounds__(256) void k_attn(const float* __restrict__ z,
                                              const float* __restrict__ wq,
                                              const float* __restrict__ wk,
                                              float* __restrict__ out) {
  __shared__ float lds[8192];
  __shared__ float red[4];
  const int b = blockIdx.x >> 1, half = blockIdx.x & 1;
  const int t = threadIdx.x;
  const int lane = t & 63;
  const int w = __builtin_amdgcn_readfirstlane(t >> 6);
  const float4* zb4 = (const float4*)(z + (size_t)b * 16384);

  float qa[4][8], ka[4][8];
#pragma unroll
  for (int hh = 0; hh < 4; ++hh)
#pragma unroll
    for (int j = 0; j < 8; ++j) { qa[hh][j] = 0.f; ka[hh][j] = 0.f; }

  float4* lds4 = (float4*)lds;
  for (int dc = 0; dc < 2; ++dc) {
    __syncthreads();
    for (int i = t; i < 2048; i += 256) {
      int p = i >> 5, ld4 = i & 31;
      lds4[ld4 * 64 + (p ^ (ld4 & 7))] = zb4[p * 64 + dc * 32 + ld4];
    }
    __syncthreads();
#pragma unroll
    for (int hh = 0; hh < 4; ++hh) {
      int h = half * 4 + hh;
      const float* Wqb = wq + (size_t)h * 8192 + (size_t)(w * 8) * 256 + dc * 128;
      const float* Wkb = wk + (size_t)h * 8192 + (size_t)(w * 8) * 256 + dc * 128;
      for (int ld4 = 0; ld4 < 32; ++ld4) {
        float4 wv[8], kv[8];
#pragma unroll
        for (int j = 0; j < 8; ++j) {
          wv[j] = *(const float4*)(Wqb + j * 256 + ld4 * 4);
          kv[j] = *(const float4*)(Wkb + j * 256 + ld4 * 4);
        }
        float4 zv = lds4[ld4 * 64 + (lane ^ (ld4 & 7))];
#pragma unroll
        for (int j = 0; j < 8; ++j) {
          qa[hh][j] = fmaf(wv[j].x, zv.x, fmaf(wv[j].y, zv.y,
                      fmaf(wv[j].z, zv.z, fmaf(wv[j].w, zv.w, qa[hh][j]))));
          ka[hh][j] = fmaf(kv[j].x, zv.x, fmaf(kv[j].y, zv.y,
                      fmaf(kv[j].z, zv.z, fmaf(kv[j].w, zv.w, ka[hh][j]))));
        }
      }
    }
  }

  float* Qs = lds;
  float* Ks = lds + 2048;
  float lse = 0.f;
#pragma unroll
  for (int hh = 0; hh < 4; ++hh) {
    __syncthreads();
#pragma unroll
    for (int j = 0; j < 8; ++j) {
      Qs[(w * 8 + j) * 64 + lane] = qa[hh][j];
      Ks[(w * 8 + j) * 64 + lane] = ka[hh][j];
    }
    __syncthreads();
    float av[16];
#pragma unroll
    for (int mm = 0; mm < 16; ++mm) av[mm] = 0.f;
    for (int rr = 0; rr < 32; ++rr) {
      float kv = Ks[rr * 64 + lane];
      const float* qrow = &Qs[rr * 64 + w * 16];
      float4 q0 = *(const float4*)(qrow + 0);
      float4 q1 = *(const float4*)(qrow + 4);
      float4 q2 = *(const float4*)(qrow + 8);
      float4 q3 = *(const float4*)(qrow + 12);
      av[0]  = fmaf(q0.x, kv, av[0]);  av[1]  = fmaf(q0.y, kv, av[1]);
      av[2]  = fmaf(q0.z, kv, av[2]);  av[3]  = fmaf(q0.w, kv, av[3]);
      av[4]  = fmaf(q1.x, kv, av[4]);  av[5]  = fmaf(q1.y, kv, av[5]);
      av[6]  = fmaf(q1.z, kv, av[6]);  av[7]  = fmaf(q1.w, kv, av[7]);
      av[8]  = fmaf(q2.x, kv, av[8]);  av[9]  = fmaf(q2.y, kv, av[9]);
      av[10] = fmaf(q2.z, kv, av[10]); av[11] = fmaf(q2.w, kv, av[11]);
      av[12] = fmaf(q3.x, kv, av[12]); av[13] = fmaf(q3.y, kv, av[13]);
      av[14] = fmaf(q3.z, kv, av[14]); av[15] = fmaf(q3.w, kv, av[15]);
    }
#pragma unroll
    for (int mm = 0; mm < 16; ++mm) {
      float e = __expf(GAMMA * av[mm]);
#pragma unroll
      for (int off = 32; off; off >>= 1) e += __shfl_xor(e, off, 64);
      lse += __logf(e);
    }
  }
  if (lane == 0) red[w] = lse;
  __syncthreads();
  if (t == 0)
    atomicAdd(out + b, -(red[0] + red[1] + red[2] + red[3]) * (1.0f / GAMMA));
}

// ---------------------------------------------------------------------------
extern "C" void kernel_launch(void* const* d_in, const int* in_sizes, int n_in,
                              void* d_out, int out_size, void* d_ws,
                              size_t ws_size, hipStream_t stream) {
  (void)in_sizes; (void)n_in; (void)out_size;
  const float* x  = (const float*)d_in[0];
  const float* z  = (const float*)d_in[1];
  const float* ew = (const float*)d_in[2];
  const float* eb = (const float*)d_in[3];
  const float* vb = (const float*)d_in[4];
  const float* pb = (const float*)d_in[5];
  const float* mw = (const float*)d_in[6];
  const float* wq = (const float*)d_in[7];
  const float* wk = (const float*)d_in[8];
  float* out = (float*)d_out;

  const size_t Z_B  = (size_t)1024 * 64 * 256 * 2;  // 33.55 MB zb16
  const size_t MT_B = (size_t)1024 * 256 * 2;       // 0.52 MB mt16
  const size_t W_B  = (size_t)8 * 32 * 256 * 2;     // 128 KB each wq16/wk16
  const size_t X_B  = (size_t)1024 * 12288 * 2;     // 25.17 MB x16
  const size_t EW_B = (size_t)256 * 192 * 2;        // 96 KB ew16
  const size_t FULL = Z_B + MT_B + 2 * W_B + X_B + EW_B;  // ~59.6 MB
  const size_t MID  = Z_B + MT_B + 2 * W_B;               // ~34.3 MB

  ushort* zb16 = (ushort*)d_ws;
  ushort* mt16 = (ushort*)((char*)d_ws + Z_B);
  ushort* wq16 = (ushort*)((char*)d_ws + Z_B + MT_B);
  ushort* wk16 = (ushort*)((char*)d_ws + Z_B + MT_B + W_B);
  ushort* x16  = (ushort*)((char*)d_ws + Z_B + MT_B + 2 * W_B);
  ushort* ew16 = (ushort*)((char*)d_ws + Z_B + MT_B + 2 * W_B + X_B);

  if (ws_size >= FULL) {
    k_xz_cvt<<<1024, 256, 0, stream>>>(x, z, vb, eb, pb, out, x16, zb16);
    k_cvt_weights<<<304, 256, 0, stream>>>(
        (const float4*)wq, (const float4*)wk, (const float4*)ew, mw,
        (ushort4*)wq16, (ushort4*)wk16, (ushort4*)ew16, mt16);
    k_enc_mfma <<<1024, 256, 0, stream>>>(x16, ew16, z, out);
    k_mem_mfma <<<4096, 256, 0, stream>>>(zb16, mt16, out);
    k_attn_mfma<<<1024, 256, 0, stream>>>(zb16, wq16, wk16, out);
  } else if (ws_size >= MID) {
    k_xz  <<<1024, 256, 0, stream>>>(x, z, vb, eb, pb, out);
    k_enc <<<1024, 256, 0, stream>>>(x, z, ew, out);
    k_cvt    <<<16384, 256, 0, stream>>>((const float4*)z, (ushort4*)zb16);
    k_cvt    <<<64, 256, 0, stream>>>((const float4*)wq, (ushort4*)wq16);
    k_cvt    <<<64, 256, 0, stream>>>((const float4*)wk, (ushort4*)wk16);
    k_cvt_mw <<<128, 256, 0, stream>>>(mw, mt16);
    k_mem_mfma <<<4096, 256, 0, stream>>>(zb16, mt16, out);
    k_attn_mfma<<<1024, 256, 0, stream>>>(zb16, wq16, wk16, out);
  } else {
    k_xz  <<<1024, 256, 0, stream>>>(x, z, vb, eb, pb, out);
    k_enc <<<1024, 256, 0, stream>>>(x, z, ew, out);
    k_mem <<<4096, 256, 0, stream>>>(z, mw, out);
    k_attn<<<2048, 256, 0, stream>>>(z, wq, wk, out);
  }
}

// Round 9
// 406.774 us; speedup vs baseline: 6.7909x; 1.0701x over previous
//
#include <hip/hip_runtime.h>
#include <hip/hip_bf16.h>

#define GAMMA 0.25f

// Shapes: B=1024, C=3, H=64, D=256, NP=64 (8x8 grid of 8x8 patches),
//         M=1024, NH=8, R=32, P=8.  fp32 in/out.  out[b] = quad - coupling.

typedef __attribute__((ext_vector_type(8))) short short8;  // 8 bf16 (4 VGPRs)
typedef __attribute__((ext_vector_type(4))) float f32x4;   // 4 fp32 acc

__device__ __forceinline__ float dot4(float4 a, float4 b) {
  return fmaf(a.x, b.x, fmaf(a.y, b.y, fmaf(a.z, b.z, a.w * b.w)));
}

__device__ __forceinline__ void fma4(float4& a, float s, float4 w) {
  a.x = fmaf(s, w.x, a.x); a.y = fmaf(s, w.y, a.y);
  a.z = fmaf(s, w.z, a.z); a.w = fmaf(s, w.w, a.w);
}

__device__ __forceinline__ ushort f2bf(float f) {
  __hip_bfloat16 h = __float2bfloat16(f);  // RNE
  return *reinterpret_cast<ushort*>(&h);
}

// 256-thread block sum; result valid on all threads.
__device__ __forceinline__ float block_sum_256(float v, float* tmp) {
#pragma unroll
  for (int off = 32; off; off >>= 1) v += __shfl_down(v, off, 64);
  int w = threadIdx.x >> 6;
  if ((threadIdx.x & 63) == 0) tmp[w] = v;
  __syncthreads();
  return tmp[0] + tmp[1] + tmp[2] + tmp[3];
}

// ---------------------------------------------------------------------------
// Kernel 1 (fused): quad/vis/bias/pos terms AND x,z -> bf16 conversion.
// ---------------------------------------------------------------------------
__global__ __launch_bounds__(256) void k_xz_cvt(const float* __restrict__ x,
                                                const float* __restrict__ z,
                                                const float* __restrict__ vb,
                                                const float* __restrict__ eb,
                                                const float* __restrict__ pb,
                                                float* __restrict__ out,
                                                ushort* __restrict__ x16,
                                                ushort* __restrict__ zb16) {
  __shared__ float tmp[4];
  int b = blockIdx.x, t = threadIdx.x;
  const float4* xb = (const float4*)(x + (size_t)b * 12288);
  const float4* vb4 = (const float4*)vb;
  ushort4* x16o = (ushort4*)(x16 + (size_t)b * 12288);
  float s = 0.f;
  for (int i = t; i < 3072; i += 256) {
    float4 xv = xb[i];
    float4 bv = vb4[i];
    s += 0.5f * dot4(xv, xv) - dot4(bv, xv);
    ushort4 o;
    o.x = f2bf(xv.x); o.y = f2bf(xv.y); o.z = f2bf(xv.z); o.w = f2bf(xv.w);
    x16o[i] = o;
  }
  const float4* zb = (const float4*)(z + (size_t)b * 16384);
  const float4* pb4 = (const float4*)pb;
  const float4* eb4 = (const float4*)eb;
  ushort4* z16o = (ushort4*)(zb16 + (size_t)b * 16384);
  for (int i = t; i < 4096; i += 256) {
    float4 zv = zb[i];
    float4 pv = pb4[i];
    float4 ev = eb4[i & 63];
    float4 c;
    c.x = pv.x + ev.x; c.y = pv.y + ev.y; c.z = pv.z + ev.z; c.w = pv.w + ev.w;
    s += 0.5f * dot4(zv, zv) - dot4(zv, c);
    ushort4 o;
    o.x = f2bf(zv.x); o.y = f2bf(zv.y); o.z = f2bf(zv.z); o.w = f2bf(zv.w);
    z16o[i] = o;
  }
  float r = block_sum_256(s, tmp);
  if (t == 0) out[b] = r;
}

// ---------------------------------------------------------------------------
// All small weight conversions in ONE launch (block ranges):
// [0,64) wq plain, [64,128) wk plain, [128,176) ew plain, [176,304) mw-transp.
// ---------------------------------------------------------------------------
__global__ __launch_bounds__(256) void k_cvt_weights(
    const float4* __restrict__ wq4, const float4* __restrict__ wk4,
    const float4* __restrict__ ew4, const float* __restrict__ mw,
    ushort4* __restrict__ wq16, ushort4* __restrict__ wk16,
    ushort4* __restrict__ ew16, ushort* __restrict__ mt) {
  int bid = blockIdx.x, t = threadIdx.x;
  if (bid < 176) {
    const float4* src; ushort4* dst; int i;
    if (bid < 64)       { src = wq4; dst = wq16; i = bid * 256 + t; }
    else if (bid < 128) { src = wk4; dst = wk16; i = (bid - 64) * 256 + t; }
    else                { src = ew4; dst = ew16; i = (bid - 128) * 256 + t; }
    float4 v = src[i];
    ushort4 o;
    o.x = f2bf(v.x); o.y = f2bf(v.y); o.z = f2bf(v.z); o.w = f2bf(v.w);
    dst[i] = o;
  } else {
    int j = (bid - 176) * 256 + t;  // 32768 threads
    int m = j >> 5, k8 = j & 31;
    ushort tmp[8];
#pragma unroll
    for (int i = 0; i < 8; ++i)
      tmp[i] = f2bf(mw[(size_t)(k8 * 8 + i) * 1024 + m]);
    ushort4 a, c;
    a.x = tmp[0]; a.y = tmp[1]; a.z = tmp[2]; a.w = tmp[3];
    c.x = tmp[4]; c.y = tmp[5]; c.z = tmp[6]; c.w = tmp[7];
    *(ushort4*)(mt + (size_t)m * 256 + k8 * 8) = a;
    *(ushort4*)(mt + (size_t)m * 256 + k8 * 8 + 4) = c;
  }
}

// ---------------------------------------------------------------------------
// Kernel 2 (MFMA): phi_enc. (unchanged from R8)
// ---------------------------------------------------------------------------
__global__ __launch_bounds__(256) void k_enc_mfma(const ushort* __restrict__ x16,
                                                  const ushort* __restrict__ ew16,
                                                  const float* __restrict__ z,
                                                  float* __restrict__ out) {
  __shared__ ushort bfr[2][1024 * 8];  // 2 x 16 KB
  __shared__ float tmp[4];
  const int t = threadIdx.x, l = t & 63, w = t >> 6;
  const int q = l >> 4, m = l & 15;
  const int b = blockIdx.x;

  const int p = 16 * w + m, gi = p >> 3, gj = p & 7;
  short8 a[6];
#pragma unroll
  for (int ks = 0; ks < 6; ++ks) {
    int k0 = ks * 32 + q * 8;
    int c = k0 >> 6, ii = (k0 & 63) >> 3;
    a[ks] = *(const short8*)(x16 + (size_t)b * 12288 + c * 4096 +
                             (gi * 8 + ii) * 64 + gj * 8);
  }
#pragma unroll
  for (int j = 0; j < 4; ++j) {
    int i2 = t + j * 256, l2 = i2 & 63, ct = i2 >> 6;
    short8 v = *(const short8*)(ew16 + (size_t)(16 * ct + (l2 & 15)) * 192 +
                                (l2 >> 4) * 8);
    *(short8*)(bfr[0] + (size_t)i2 * 8) = v;
  }
  __syncthreads();

  f32x4 acc[16];
#pragma unroll
  for (int c = 0; c < 16; ++c) acc[c] = f32x4{0.f, 0.f, 0.f, 0.f};

  for (int ks = 0; ks < 6; ++ks) {
    int cur = ks & 1;
    short8 pre[4];
    if (ks < 5) {
#pragma unroll
      for (int j = 0; j < 4; ++j) {
        int i2 = t + j * 256, l2 = i2 & 63, ct = i2 >> 6;
        pre[j] = *(const short8*)(ew16 + (size_t)(16 * ct + (l2 & 15)) * 192 +
                                  (ks + 1) * 32 + (l2 >> 4) * 8);
      }
    }
#pragma unroll
    for (int ct = 0; ct < 16; ++ct) {
      short8 bv = *(const short8*)(bfr[cur] + (size_t)(ct * 64 + l) * 8);
      acc[ct] = __builtin_amdgcn_mfma_f32_16x16x32_bf16(a[ks], bv, acc[ct], 0, 0, 0);
    }
    if (ks < 5) {
#pragma unroll
      for (int j = 0; j < 4; ++j)
        *(short8*)(bfr[cur ^ 1] + (size_t)(t + j * 256) * 8) = pre[j];
    }
    __syncthreads();
  }

  const float* zb = z + (size_t)b * 16384;
  float s = 0.f;
#pragma unroll
  for (int ct = 0; ct < 16; ++ct) {
#pragma unroll
    for (int reg = 0; reg < 4; ++reg) {
      int pp = 16 * w + 4 * q + reg;
      s = fmaf(acc[ct][reg], zb[pp * 256 + 16 * ct + m], s);
    }
  }
  float r = block_sum_256(s, tmp);
  if (t == 0) atomicAdd(out + b, -r);
}

// ---------------------------------------------------------------------------
// Kernel 3 (MFMA v2): phi_mem. (unchanged from R7/R8)
// ---------------------------------------------------------------------------
__global__ __launch_bounds__(256) void k_mem_mfma(const ushort* __restrict__ zb,
                                                  const ushort* __restrict__ mt,
                                                  float* __restrict__ out) {
  __shared__ ushort zf[2048 * 8];     // 32 KB: z[b] fragment-ordered
  __shared__ ushort bf[2][1024 * 8];  // 2 x 16 KB: mt chunk double-buffer
  __shared__ float tmp[4];
  const int t = threadIdx.x, l = t & 63, w = t >> 6;
  const int b = blockIdx.x >> 2, ct = blockIdx.x & 3;

#pragma unroll
  for (int j = 0; j < 8; ++j) {
    int i = t + j * 256;
    int l2 = i & 63, ks = (i >> 6) & 7, w2 = i >> 9;
    short8 v = *(const short8*)(zb + ((size_t)b * 64 + 16 * w2 + (l2 & 15)) * 256
                                + ks * 32 + (l2 >> 4) * 8);
    *(short8*)(zf + (size_t)i * 8) = v;
  }
#pragma unroll
  for (int j = 0; j < 4; ++j) {
    int i = t + j * 256;
    int l2 = i & 63, c = i >> 6;
    short8 v = *(const short8*)(mt + ((size_t)ct * 256 + 16 * c + (l2 & 15)) * 256
                                + (l2 >> 4) * 8);
    *(short8*)(bf[0] + (size_t)i * 8) = v;
  }
  __syncthreads();

  f32x4 acc[16];
#pragma unroll
  for (int c = 0; c < 16; ++c) acc[c] = f32x4{0.f, 0.f, 0.f, 0.f};

  for (int kc = 0; kc < 8; ++kc) {
    int cur = kc & 1;
    short8 pre[4];
    if (kc < 7) {
#pragma unroll
      for (int j = 0; j < 4; ++j) {
        int i = t + j * 256;
        int l2 = i & 63, c = i >> 6;
        pre[j] = *(const short8*)(mt + ((size_t)ct * 256 + 16 * c + (l2 & 15)) * 256
                                  + (kc + 1) * 32 + (l2 >> 4) * 8);
      }
    }
    short8 az = *(const short8*)(zf + (size_t)((w * 8 + kc) * 64 + l) * 8);
#pragma unroll
    for (int c = 0; c < 16; ++c) {
      short8 bv = *(const short8*)(bf[cur] + (size_t)(c * 64 + l) * 8);
      acc[c] = __builtin_amdgcn_mfma_f32_16x16x32_bf16(az, bv, acc[c], 0, 0, 0);
    }
    if (kc < 7) {
#pragma unroll
      for (int j = 0; j < 4; ++j)
        *(short8*)(bf[cur ^ 1] + (size_t)(t + j * 256) * 8) = pre[j];
    }
    __syncthreads();
  }

  float s = 0.f;
#pragma unroll
  for (int c = 0; c < 16; ++c) {
#pragma unroll
    for (int e = 0; e < 4; ++e) {
      float r = fmaxf(acc[c][e], 0.f);
      s = fmaf(r, r, s);
    }
  }
  float r = block_sum_256(s, tmp);
  if (t == 0) atomicAdd(out + b, -r);
}

// ---------------------------------------------------------------------------
// Kernel 4 (MFMA v2): phi_att. Block = (b, half) -> 4 heads, grid 2048.
// R8 post-mortem: v1 allocated Qb/Kb for all 8 heads (80 KB LDS) -> 1
// block/CU, occupancy 11%, nothing to hide the per-head L2 W-loads behind
// (MfmaUtil 4.8%). v2 holds ONE head's Qb/Kb (10.25 KB) and caps VGPR at 128
// via __launch_bounds__(256,4) -> 4 blocks/CU, 16 waves/CU: W-load latency
// hidden by block-level overlap (same mechanism as R3->R4, R6->R7).
// Per head: phase-1 proj MFMA (W from global, L2-hot), D->bf16->LDS
// (stride-40 rows: 2-way bank aliasing only, free per m136); barrier;
// phase-2 A=QK^T (one K=32 MFMA per n-tile), exp/shfl/log; barrier.
// ---------------------------------------------------------------------------
__global__ __launch_bounds__(256, 4) void k_attn_mfma(
    const ushort* __restrict__ zb, const ushort* __restrict__ wq16,
    const ushort* __restrict__ wk16, float* __restrict__ out) {
  __shared__ ushort Qb[64 * 40];  // one head: [p][r], stride 40 halfwords
  __shared__ ushort Kb[64 * 40];
  __shared__ float tmp[4];
  const int t = threadIdx.x, l = t & 63, w = t >> 6;
  const int b = blockIdx.x >> 1, half = blockIdx.x & 1;
  const int q = l >> 4, m = l & 15;

  // A-fragments of z[b] for m-tile w: reused across 4 heads and Q/K.
  const ushort* Az = zb + ((size_t)b * 64 + 16 * w + m) * 256 + q * 8;
  short8 a[8];
#pragma unroll
  for (int ks = 0; ks < 8; ++ks) a[ks] = *(const short8*)(Az + ks * 32);

  float part = 0.f;
  for (int hh = 0; hh < 4; ++hh) {
    const int h = half * 4 + hh;
    f32x4 accq0 = f32x4{0.f, 0.f, 0.f, 0.f}, accq1 = accq0;
    f32x4 acck0 = accq0, acck1 = accq0;
    const ushort* Bq = wq16 + (size_t)h * 8192 + (size_t)m * 256 + q * 8;
    const ushort* Bk = wk16 + (size_t)h * 8192 + (size_t)m * 256 + q * 8;
#pragma unroll
    for (int ks = 0; ks < 8; ++ks) {
      short8 bq0 = *(const short8*)(Bq + ks * 32);
      short8 bq1 = *(const short8*)(Bq + 4096 + ks * 32);
      short8 bk0 = *(const short8*)(Bk + ks * 32);
      short8 bk1 = *(const short8*)(Bk + 4096 + ks * 32);
      accq0 = __builtin_amdgcn_mfma_f32_16x16x32_bf16(a[ks], bq0, accq0, 0, 0, 0);
      accq1 = __builtin_amdgcn_mfma_f32_16x16x32_bf16(a[ks], bq1, accq1, 0, 0, 0);
      acck0 = __builtin_amdgcn_mfma_f32_16x16x32_bf16(a[ks], bk0, acck0, 0, 0, 0);
      acck1 = __builtin_amdgcn_mfma_f32_16x16x32_bf16(a[ks], bk1, acck1, 0, 0, 0);
    }
    // D (row = 16w+4q+reg, col = r) -> bf16 -> LDS.
    const int rowbase = (16 * w + 4 * q) * 40;
#pragma unroll
    for (int reg = 0; reg < 4; ++reg) {
      Qb[rowbase + reg * 40 + m]      = f2bf(accq0[reg]);
      Qb[rowbase + reg * 40 + 16 + m] = f2bf(accq1[reg]);
      Kb[rowbase + reg * 40 + m]      = f2bf(acck0[reg]);
      Kb[rowbase + reg * 40 + 16 + m] = f2bf(acck1[reg]);
    }
    __syncthreads();

    // Phase 2: A-frag rows 16w+m, k=r=q*8..+7; B-frags from Kb per n-tile.
    short8 qa = *(const short8*)&Qb[(16 * w + m) * 40 + q * 8];
    f32x4 acc[4];
#pragma unroll
    for (int nt = 0; nt < 4; ++nt) {
      short8 kb = *(const short8*)&Kb[(16 * nt + m) * 40 + q * 8];
      acc[nt] = __builtin_amdgcn_mfma_f32_16x16x32_bf16(
          qa, kb, f32x4{0.f, 0.f, 0.f, 0.f}, 0, 0, 0);
    }
#pragma unroll
    for (int reg = 0; reg < 4; ++reg) {
      float e = __expf(GAMMA * acc[0][reg]) + __expf(GAMMA * acc[1][reg]) +
                __expf(GAMMA * acc[2][reg]) + __expf(GAMMA * acc[3][reg]);
      e += __shfl_xor(e, 1, 64);
      e += __shfl_xor(e, 2, 64);
      e += __shfl_xor(e, 4, 64);
      e += __shfl_xor(e, 8, 64);
      part += (m == 0) ? __logf(e) : 0.f;  // one log per row 16w+4q+reg
    }
    __syncthreads();  // all Qb/Kb reads done before next head's writes
  }
  float tot = block_sum_256(part, tmp);
  if (t == 0) atomicAdd(out + b, -tot * (1.0f / GAMMA));
}

// ---------------------------------------------------------------------------
// Fallback kernels (mid/low ws tiers).
// ---------------------------------------------------------------------------
__global__ __launch_bounds__(256) void k_xz(const float* __restrict__ x,
                                            const float* __restrict__ z,
                                            const float* __restrict__ vb,
                                            const float* __restrict__ eb,
                                            const float* __restrict__ pb,
                                            float* __restrict__ out) {
  __shared__ float tmp[4];
  int b = blockIdx.x, t = threadIdx.x;
  const float4* xb = (const float4*)(x + (size_t)b * 12288);
  const float4* vb4 = (const float4*)vb;
  float s = 0.f;
  for (int i = t; i < 3072; i += 256) {
    float4 xv = xb[i];
    float4 bv = vb4[i];
    s += 0.5f * dot4(xv, xv) - dot4(bv, xv);
  }
  const float4* zb = (const float4*)(z + (size_t)b * 16384);
  const float4* pb4 = (const float4*)pb;
  const float4* eb4 = (const float4*)eb;
  for (int i = t; i < 4096; i += 256) {
    float4 zv = zb[i];
    float4 pv = pb4[i];
    float4 ev = eb4[i & 63];
    float4 c;
    c.x = pv.x + ev.x; c.y = pv.y + ev.y; c.z = pv.z + ev.z; c.w = pv.w + ev.w;
    s += 0.5f * dot4(zv, zv) - dot4(zv, c);
  }
  float r = block_sum_256(s, tmp);
  if (t == 0) out[b] = r;
}

__global__ __launch_bounds__(256) void k_enc(const float* __restrict__ x,
                                             const float* __restrict__ z,
                                             const float* __restrict__ ew,
                                             float* __restrict__ out) {
  __shared__ float xs[12288];
  __shared__ float tmp[4];
  int b = blockIdx.x, t = threadIdx.x;
  const float4* xb4 = (const float4*)(x + (size_t)b * 12288);
  for (int i = t; i < 3072; i += 256) ((float4*)xs)[i] = xb4[i];
  __syncthreads();

  float acc[64];
#pragma unroll
  for (int p = 0; p < 64; ++p) acc[p] = 0.f;

  for (int k4 = 0; k4 < 48; ++k4) {
    float4 wv = *(const float4*)(ew + (size_t)t * 192 + k4 * 4);
    int c = k4 >> 4;
    int ii = (k4 >> 1) & 7;
    int jh = (k4 & 1) * 4;
    const float* base = xs + c * 4096 + ii * 64 + jh;
#pragma unroll
    for (int p = 0; p < 64; ++p) {
      float4 pv = *(const float4*)(base + (p >> 3) * 512 + (p & 7) * 8);
      acc[p] = fmaf(wv.x, pv.x,
               fmaf(wv.y, pv.y, fmaf(wv.z, pv.z, fmaf(wv.w, pv.w, acc[p]))));
    }
  }
  const float* zb = z + (size_t)b * 16384;
  float s = 0.f;
#pragma unroll
  for (int p = 0; p < 64; ++p) s += acc[p] * zb[p * 256 + t];
  float r = block_sum_256(s, tmp);
  if (t == 0) atomicAdd(out + b, -r);
}

__global__ __launch_bounds__(256) void k_cvt(const float4* __restrict__ z4,
                                             ushort4* __restrict__ o4) {
  int i = blockIdx.x * 256 + threadIdx.x;
  float4 v = z4[i];
  ushort4 o;
  o.x = f2bf(v.x); o.y = f2bf(v.y); o.z = f2bf(v.z); o.w = f2bf(v.w);
  o4[i] = o;
}

__global__ __launch_bounds__(256) void k_cvt_mw(const float* __restrict__ mw,
                                                ushort* __restrict__ mt) {
  int j = blockIdx.x * 256 + threadIdx.x;
  int m = j >> 5, k8 = j & 31;
  ushort tmp[8];
#pragma unroll
  for (int i = 0; i < 8; ++i) tmp[i] = f2bf(mw[(size_t)(k8 * 8 + i) * 1024 + m]);
  ushort4 a, c;
  a.x = tmp[0]; a.y = tmp[1]; a.z = tmp[2]; a.w = tmp[3];
  c.x = tmp[4]; c.y = tmp[5]; c.z = tmp[6]; c.w = tmp[7];
  *(ushort4*)(mt + (size_t)m * 256 + k8 * 8) = a;
  *(ushort4*)(mt + (size_t)m * 256 + k8 * 8 + 4) = c;
}

__global__ __launch_bounds__(256) void k_mem(const float* __restrict__ z,
                                             const float* __restrict__ mw,
                                             float* __restrict__ out) {
  __shared__ float zs[16 * 256];
  __shared__ float tmp[4];
  int b = blockIdx.x >> 2, pt = blockIdx.x & 3, t = threadIdx.x;
  const float4* zb4 = (const float4*)(z + (size_t)b * 16384 + pt * 4096);
  for (int i = t; i < 1024; i += 256) ((float4*)zs)[i] = zb4[i];
  __syncthreads();

  const float4* m4 = (const float4*)mw;
  float4 acc[16];
#pragma unroll
  for (int pp = 0; pp < 16; ++pp) acc[pp] = make_float4(0.f, 0.f, 0.f, 0.f);

#pragma unroll 2
  for (int k4 = 0; k4 < 64; ++k4) {
    float4 w0 = m4[(4 * k4 + 0) * 256 + t];
    float4 w1 = m4[(4 * k4 + 1) * 256 + t];
    float4 w2 = m4[(4 * k4 + 2) * 256 + t];
    float4 w3 = m4[(4 * k4 + 3) * 256 + t];
#pragma unroll
    for (int pp = 0; pp < 16; ++pp) {
      float4 zv = *(const float4*)&zs[pp * 256 + k4 * 4];
      fma4(acc[pp], zv.x, w0);
      fma4(acc[pp], zv.y, w1);
      fma4(acc[pp], zv.z, w2);
      fma4(acc[pp], zv.w, w3);
    }
  }
  float total = 0.f;
#pragma unroll
  for (int pp = 0; pp < 16; ++pp) {
    float r;
    r = fmaxf(acc[pp].x, 0.f); total = fmaf(r, r, total);
    r = fmaxf(acc[pp].y, 0.f); total = fmaf(r, r, total);
    r = fmaxf(acc[pp].z, 0.f); total = fmaf(r, r, total);
    r = fmaxf(acc[pp].w, 0.f); total = fmaf(r, r, total);
  }
  float r = block_sum_256(total, tmp);
  if (t == 0) atomicAdd(out + b, -r);
}

__global__ __launch_bounds__(256) void k_attn(const float* __restrict__ z,
                                              const float* __restrict__ wq,
                                              const float* __restrict__ wk,
                                              float* __restrict__ out) {
  __shared__ float lds[8192];
  __shared__ float red[4];
  const int b = blockIdx.x >> 1, half = blockIdx.x & 1;
  const int t = threadIdx.x;
  const int lane = t & 63;
  const int w = __builtin_amdgcn_readfirstlane(t >> 6);
  const float4* zb4 = (const float4*)(z + (size_t)b * 16384);

  float qa[4][8], ka[4][8];
#pragma unroll
  for (int hh = 0; hh < 4; ++hh)
#pragma unroll
    for (int j = 0; j < 8; ++j) { qa[hh][j] = 0.f; ka[hh][j] = 0.f; }

  float4* lds4 = (float4*)lds;
  for (int dc = 0; dc < 2; ++dc) {
    __syncthreads();
    for (int i = t; i < 2048; i += 256) {
      int p = i >> 5, ld4 = i & 31;
      lds4[ld4 * 64 + (p ^ (ld4 & 7))] = zb4[p * 64 + dc * 32 + ld4];
    }
    __syncthreads();
#pragma unroll
    for (int hh = 0; hh < 4; ++hh) {
      int h = half * 4 + hh;
      const float* Wqb = wq + (size_t)h * 8192 + (size_t)(w * 8) * 256 + dc * 128;
      const float* Wkb = wk + (size_t)h * 8192 + (size_t)(w * 8) * 256 + dc * 128;
      for (int ld4 = 0; ld4 < 32; ++ld4) {
        float4 wv[8], kv[8];
#pragma unroll
        for (int j = 0; j < 8; ++j) {
          wv[j] = *(const float4*)(Wqb + j * 256 + ld4 * 4);
          kv[j] = *(const float4*)(Wkb + j * 256 + ld4 * 4);
        }
        float4 zv = lds4[ld4 * 64 + (lane ^ (ld4 & 7))];
#pragma unroll
        for (int j = 0; j < 8; ++j) {
          qa[hh][j] = fmaf(wv[j].x, zv.x, fmaf(wv[j].y, zv.y,
                      fmaf(wv[j].z, zv.z, fmaf(wv[j].w, zv.w, qa[hh][j]))));
          ka[hh][j] = fmaf(kv[j].x, zv.x, fmaf(kv[j].y, zv.y,
                      fmaf(kv[j].z, zv.z, fmaf(kv[j].w, zv.w, ka[hh][j]))));
        }
      }
    }
  }

  float* Qs = lds;
  float* Ks = lds + 2048;
  float lse = 0.f;
#pragma unroll
  for (int hh = 0; hh < 4; ++hh) {
    __syncthreads();
#pragma unroll
    for (int j = 0; j < 8; ++j) {
      Qs[(w * 8 + j) * 64 + lane] = qa[hh][j];
      Ks[(w * 8 + j) * 64 + lane] = ka[hh][j];
    }
    __syncthreads();
    float av[16];
#pragma unroll
    for (int mm = 0; mm < 16; ++mm) av[mm] = 0.f;
    for (int rr = 0; rr < 32; ++rr) {
      float kv = Ks[rr * 64 + lane];
      const float* qrow = &Qs[rr * 64 + w * 16];
      float4 q0 = *(const float4*)(qrow + 0);
      float4 q1 = *(const float4*)(qrow + 4);
      float4 q2 = *(const float4*)(qrow + 8);
      float4 q3 = *(const float4*)(qrow + 12);
      av[0]  = fmaf(q0.x, kv, av[0]);  av[1]  = fmaf(q0.y, kv, av[1]);
      av[2]  = fmaf(q0.z, kv, av[2]);  av[3]  = fmaf(q0.w, kv, av[3]);
      av[4]  = fmaf(q1.x, kv, av[4]);  av[5]  = fmaf(q1.y, kv, av[5]);
      av[6]  = fmaf(q1.z, kv, av[6]);  av[7]  = fmaf(q1.w, kv, av[7]);
      av[8]  = fmaf(q2.x, kv, av[8]);  av[9]  = fmaf(q2.y, kv, av[9]);
      av[10] = fmaf(q2.z, kv, av[10]); av[11] = fmaf(q2.w, kv, av[11]);
      av[12] = fmaf(q3.x, kv, av[12]); av[13] = fmaf(q3.y, kv, av[13]);
      av[14] = fmaf(q3.z, kv, av[14]); av[15] = fmaf(q3.w, kv, av[15]);
    }
#pragma unroll
    for (int mm = 0; mm < 16; ++mm) {
      float e = __expf(GAMMA * av[mm]);
#pragma unroll
      for (int off = 32; off; off >>= 1) e += __shfl_xor(e, off, 64);
      lse += __logf(e);
    }
  }
  if (lane == 0) red[w] = lse;
  __syncthreads();
  if (t == 0)
    atomicAdd(out + b, -(red[0] + red[1] + red[2] + red[3]) * (1.0f / GAMMA));
}

// ---------------------------------------------------------------------------
extern "C" void kernel_launch(void* const* d_in, const int* in_sizes, int n_in,
                              void* d_out, int out_size, void* d_ws,
                              size_t ws_size, hipStream_t stream) {
  (void)in_sizes; (void)n_in; (void)out_size;
  const float* x  = (const float*)d_in[0];
  const float* z  = (const float*)d_in[1];
  const float* ew = (const float*)d_in[2];
  const float* eb = (const float*)d_in[3];
  const float* vb = (const float*)d_in[4];
  const float* pb = (const float*)d_in[5];
  const float* mw = (const float*)d_in[6];
  const float* wq = (const float*)d_in[7];
  const float* wk = (const float*)d_in[8];
  float* out = (float*)d_out;

  const size_t Z_B  = (size_t)1024 * 64 * 256 * 2;  // 33.55 MB zb16
  const size_t MT_B = (size_t)1024 * 256 * 2;       // 0.52 MB mt16
  const size_t W_B  = (size_t)8 * 32 * 256 * 2;     // 128 KB each wq16/wk16
  const size_t X_B  = (size_t)1024 * 12288 * 2;     // 25.17 MB x16
  const size_t EW_B = (size_t)256 * 192 * 2;        // 96 KB ew16
  const size_t FULL = Z_B + MT_B + 2 * W_B + X_B + EW_B;  // ~59.6 MB
  const size_t MID  = Z_B + MT_B + 2 * W_B;               // ~34.3 MB

  ushort* zb16 = (ushort*)d_ws;
  ushort* mt16 = (ushort*)((char*)d_ws + Z_B);
  ushort* wq16 = (ushort*)((char*)d_ws + Z_B + MT_B);
  ushort* wk16 = (ushort*)((char*)d_ws + Z_B + MT_B + W_B);
  ushort* x16  = (ushort*)((char*)d_ws + Z_B + MT_B + 2 * W_B);
  ushort* ew16 = (ushort*)((char*)d_ws + Z_B + MT_B + 2 * W_B + X_B);

  if (ws_size >= FULL) {
    k_xz_cvt<<<1024, 256, 0, stream>>>(x, z, vb, eb, pb, out, x16, zb16);
    k_cvt_weights<<<304, 256, 0, stream>>>(
        (const float4*)wq, (const float4*)wk, (const float4*)ew, mw,
        (ushort4*)wq16, (ushort4*)wk16, (ushort4*)ew16, mt16);
    k_enc_mfma <<<1024, 256, 0, stream>>>(x16, ew16, z, out);
    k_mem_mfma <<<4096, 256, 0, stream>>>(zb16, mt16, out);
    k_attn_mfma<<<2048, 256, 0, stream>>>(zb16, wq16, wk16, out);
  } else if (ws_size >= MID) {
    k_xz  <<<1024, 256, 0, stream>>>(x, z, vb, eb, pb, out);
    k_enc <<<1024, 256, 0, stream>>>(x, z, ew, out);
    k_cvt    <<<16384, 256, 0, stream>>>((const float4*)z, (ushort4*)zb16);
    k_cvt    <<<64, 256, 0, stream>>>((const float4*)wq, (ushort4*)wq16);
    k_cvt    <<<64, 256, 0, stream>>>((const float4*)wk, (ushort4*)wk16);
    k_cvt_mw <<<128, 256, 0, stream>>>(mw, mt16);
    k_mem_mfma <<<4096, 256, 0, stream>>>(zb16, mt16, out);
    k_attn_mfma<<<2048, 256, 0, stream>>>(zb16, wq16, wk16, out);
  } else {
    k_xz  <<<1024, 256, 0, stream>>>(x, z, vb, eb, pb, out);
    k_enc <<<1024, 256, 0, stream>>>(x, z, ew, out);
    k_mem <<<4096, 256, 0, stream>>>(z, mw, out);
    k_attn<<<2048, 256, 0, stream>>>(z, wq, wk, out);
  }
}